// Round 2
// baseline (1138.721 us; speedup 1.0000x reference)
//
#include <hip/hip_runtime.h>
#include <hip/hip_bf16.h>

#define NN 50000
#define NE 800000
#define MP 50048           // 391*128 padded rows
#define NBLK 196           // ceil(NN/256)

typedef __attribute__((ext_vector_type(8))) short short8;
typedef __attribute__((ext_vector_type(4))) float f32x4;

__device__ __forceinline__ float b2f(__hip_bfloat16 x) { return __bfloat162float(x); }
__device__ __forceinline__ __hip_bfloat16 f2b(float x) { return __float2bfloat16(x); }
__device__ __forceinline__ float sigm(float x) { return 1.f / (1.f + __expf(-x)); }
__device__ __forceinline__ float leaky(float x) { return x >= 0.f ? x : 0.2f * x; }

__device__ __forceinline__ void gload16(const void* g, void* l) {
  __builtin_amdgcn_global_load_lds((__attribute__((address_space(1))) void*)(g),
                                   (__attribute__((address_space(3))) void*)(l), 16, 0, 0);
}

__global__ void diag_kernel(float* out, float v) { out[0] = v; }

__global__ void zero_i32(int* p, int n) {
  int i = blockIdx.x * 256 + threadIdx.x;
  if (i < n) p[i] = 0;
}

__global__ void conv_kernel(const float* __restrict__ in, __hip_bfloat16* __restrict__ out, int n) {
  for (int i = blockIdx.x * blockDim.x + threadIdx.x; i < n; i += gridDim.x * blockDim.x)
    out[i] = f2b(in[i]);
}

// out[r*cols+c] = in[r*ld + coff + c]
__global__ void conv_strided(const float* __restrict__ in, __hip_bfloat16* __restrict__ out,
                             int rows, int cols, int ld, int coff) {
  int idx = blockIdx.x * 256 + threadIdx.x;
  if (idx >= rows * cols) return;
  int r = idx / cols, c = idx - r * cols;
  out[idx] = f2b(in[(size_t)r * ld + coff + c]);
}

// ---------------- unified GEMM: C = A1*B1^T (+ A2*B2^T), K=256 per pass ----------------
#define EPI_BF16 0
#define EPI_SIGM 1
#define EPI_BIAS 2
#define EPI_GRUF 3
#define EPI_GRUS 4
#define EPI_OUT  5

template <int EPI, bool DUAL>
__global__ __launch_bounds__(256) void gemm256(
    const __hip_bfloat16* __restrict__ A1, const __hip_bfloat16* __restrict__ B1,
    const __hip_bfloat16* __restrict__ A2, const __hip_bfloat16* __restrict__ B2,
    void* __restrict__ Cv, int M, int N,
    const float* __restrict__ bi, const float* __restrict__ bh,
    const __hip_bfloat16* __restrict__ RZ, const __hip_bfloat16* __restrict__ T,
    __hip_bfloat16* __restrict__ HP) {
  __shared__ __align__(16) short smem[8192];  // As[128][32] + Bs[128][32]
  short* As = smem;
  short* Bs = smem + 4096;
  const int tid = threadIdx.x;
  const int wid = tid >> 6, lane = tid & 63;
  const int m0 = blockIdx.y * 128, n0 = blockIdx.x * 128;
  const int wr = wid >> 1, wc = wid & 1;
  const int sr = lane >> 2, kp = (lane & 3) * 8;
  const int lrow = lane & 15, lk = (lane >> 4) * 8;
  f32x4 acc[4][4];
#pragma unroll
  for (int i = 0; i < 4; ++i)
#pragma unroll
    for (int j = 0; j < 4; ++j) acc[i][j] = (f32x4)0.f;

#pragma unroll
  for (int pass = 0; pass < (DUAL ? 2 : 1); ++pass) {
    const __hip_bfloat16* A = pass ? A2 : A1;
    const __hip_bfloat16* B = pass ? B2 : B1;
    for (int k0 = 0; k0 < 256; k0 += 32) {
#pragma unroll
      for (int ss = 0; ss < 2; ++ss) {
        int s = wid + ss * 4;
        gload16(A + (size_t)(m0 + s * 16 + sr) * 256 + k0 + kp, &As[s * 512]);
        gload16(B + (size_t)(n0 + s * 16 + sr) * 256 + k0 + kp, &Bs[s * 512]);
      }
      __syncthreads();
      short8 af[4], bfv[4];
#pragma unroll
      for (int i = 0; i < 4; ++i) af[i] = *(const short8*)&As[(wr * 64 + i * 16 + lrow) * 32 + lk];
#pragma unroll
      for (int j = 0; j < 4; ++j) bfv[j] = *(const short8*)&Bs[(wc * 64 + j * 16 + lrow) * 32 + lk];
#pragma unroll
      for (int i = 0; i < 4; ++i)
#pragma unroll
        for (int j = 0; j < 4; ++j)
          acc[i][j] = __builtin_amdgcn_mfma_f32_16x16x32_bf16(af[i], bfv[j], acc[i][j], 0, 0, 0);
      __syncthreads();
    }
  }

  const int rowb = m0 + wr * 64 + (lane >> 4) * 4;
  const int colb = n0 + wc * 64 + (lane & 15);
#pragma unroll
  for (int i = 0; i < 4; ++i) {
#pragma unroll
    for (int j = 0; j < 4; ++j) {
      const int col = colb + j * 16;
#pragma unroll
      for (int rr = 0; rr < 4; ++rr) {
        const int row = rowb + i * 16 + rr;
        if (row >= M) continue;
        float v = acc[i][j][rr];
        if constexpr (EPI == EPI_BF16) {
          ((__hip_bfloat16*)Cv)[(size_t)row * N + col] = f2b(v);
        } else if constexpr (EPI == EPI_SIGM) {
          ((__hip_bfloat16*)Cv)[(size_t)row * 512 + col] = f2b(sigm(v + bi[col] + bh[col]));
        } else if constexpr (EPI == EPI_BIAS) {
          ((__hip_bfloat16*)Cv)[(size_t)row * 256 + col] = f2b(v + bh[512 + col]);
        } else if constexpr (EPI == EPI_GRUF) {
          float r_ = b2f(RZ[(size_t)row * 512 + col]);
          float z_ = b2f(RZ[(size_t)row * 512 + 256 + col]);
          float n_ = tanhf(v + bi[512 + col] + r_ * bh[512 + col]);
          HP[(size_t)row * 256 + col] = f2b((1.f - z_) * n_);
        } else if constexpr (EPI == EPI_GRUS) {
          float r_ = b2f(RZ[(size_t)row * 512 + col]);
          float z_ = b2f(RZ[(size_t)row * 512 + 256 + col]);
          float t_ = b2f(T[(size_t)row * 256 + col]);          // already + bh_n
          float n_ = tanhf(v + bi[512 + col] + r_ * t_);
          float hp = b2f(HP[(size_t)row * 256 + col]);
          HP[(size_t)row * 256 + col] = f2b(hp + (1.f - z_) * n_ + z_ * hp);
        } else {  // EPI_OUT
          ((float*)Cv)[(size_t)row * 256 + col] = v;
        }
      }
    }
  }
}

// ---------------- attention logits ----------------
__global__ void esed_kernel(const __hip_bfloat16* __restrict__ z,
                            const float* __restrict__ a_s, const float* __restrict__ a_d,
                            float* __restrict__ es, float* __restrict__ ed) {
  int n = blockIdx.x;
  int wid = threadIdx.x >> 6, lane = threadIdx.x & 63;
  int h = wid >> 1;
  const float* av = (wid & 1) ? a_d : a_s;
  const __hip_bfloat16* zr = z + (size_t)n * 256 + h * 128;
  float p = b2f(zr[lane]) * av[h * 128 + lane] + b2f(zr[64 + lane]) * av[h * 128 + 64 + lane];
#pragma unroll
  for (int off = 32; off > 0; off >>= 1) p += __shfl_down(p, off, 64);
  if (lane == 0) {
    float* o = (wid & 1) ? ed : es;
    o[n * 2 + h] = p;
  }
}

// ---------------- CSR build ----------------
__global__ void hist_kernel(const int* __restrict__ dst, int* __restrict__ deg, int ne) {
  for (int e = blockIdx.x * blockDim.x + threadIdx.x; e < ne; e += gridDim.x * blockDim.x)
    atomicAdd(&deg[dst[e]], 1);
}

__global__ void scan1(const int* __restrict__ deg, int* __restrict__ bsum, int n) {
  __shared__ int sd[256];
  int idx = blockIdx.x * 256 + threadIdx.x;
  sd[threadIdx.x] = (idx < n) ? deg[idx] : 0;
  __syncthreads();
  for (int off = 128; off > 0; off >>= 1) {
    if (threadIdx.x < off) sd[threadIdx.x] += sd[threadIdx.x + off];
    __syncthreads();
  }
  if (threadIdx.x == 0) bsum[blockIdx.x] = sd[0];
}

__global__ void scan2(const int* __restrict__ bsum, int* __restrict__ boff, int nb) {
  __shared__ int s[256];
  int t = threadIdx.x;
  int v0 = (t < nb) ? bsum[t] : 0;
  s[t] = v0;
  __syncthreads();
  for (int off = 1; off < 256; off <<= 1) {
    int x = (t >= off) ? s[t - off] : 0;
    __syncthreads();
    s[t] += x;
    __syncthreads();
  }
  if (t < nb) boff[t] = s[t] - v0;
}

__global__ void scan3(const int* __restrict__ deg, const int* __restrict__ boff,
                      int* __restrict__ row_ptr, int* __restrict__ cursor, int n, int ne) {
  __shared__ int s[256];
  int t = threadIdx.x;
  int idx = blockIdx.x * 256 + t;
  int v = (idx < n) ? deg[idx] : 0;
  s[t] = v;
  __syncthreads();
  for (int off = 1; off < 256; off <<= 1) {
    int x = (t >= off) ? s[t - off] : 0;
    __syncthreads();
    s[t] += x;
    __syncthreads();
  }
  if (idx < n) {
    int val = boff[blockIdx.x] + s[t] - v;
    row_ptr[idx] = val;
    cursor[idx] = val;
  }
  if (idx == n) row_ptr[n] = ne;
}

__global__ void scatter_kernel(const int* __restrict__ src, const int* __restrict__ dst,
                               int* __restrict__ cursor, int* __restrict__ srcs, int ne) {
  for (int e = blockIdx.x * blockDim.x + threadIdx.x; e < ne; e += gridDim.x * blockDim.x) {
    int p = atomicAdd(&cursor[dst[e]], 1);
    srcs[p] = src[e];
  }
}

// ---------------- GAT aggregation ----------------
__device__ __forceinline__ void onl_upd(float& m, float& s, float v) {
  if (v <= m) {
    s += __expf(v - m);
  } else {
    s = s * __expf(m - v) + 1.f;
    m = v;
  }
}

__global__ __launch_bounds__(256) void gat_agg(const int* __restrict__ row_ptr,
                                               const int* __restrict__ srcs,
                                               const float* __restrict__ es,
                                               const float* __restrict__ ed,
                                               const __hip_bfloat16* __restrict__ z,
                                               __hip_bfloat16* __restrict__ hout) {
  int n = blockIdx.x;
  int tid = threadIdx.x;
  int start = row_ptr[n], end = row_ptr[n + 1];
  if (end - start == 0) {
    hout[(size_t)n * 256 + tid] = f2b(0.f);
    return;
  }
  float ed0 = ed[n * 2 + 0], ed1 = ed[n * 2 + 1];
  float m0 = -1e30f, s0 = 0.f, m1 = -1e30f, s1 = 0.f;
  for (int i = start + tid; i < end; i += 256) {
    int sn = srcs[i];
    onl_upd(m0, s0, leaky(es[sn * 2 + 0] + ed0));
    onl_upd(m1, s1, leaky(es[sn * 2 + 1] + ed1));
  }
  __shared__ float4 red[256];
  red[tid] = make_float4(m0, s0, m1, s1);
  __syncthreads();
  for (int off = 128; off > 0; off >>= 1) {
    if (tid < off) {
      float4 a = red[tid], b = red[tid + off];
      float mm = fmaxf(a.x, b.x);
      a.y = a.y * __expf(a.x - mm) + b.y * __expf(b.x - mm);
      a.x = mm;
      mm = fmaxf(a.z, b.z);
      a.w = a.w * __expf(a.z - mm) + b.w * __expf(b.z - mm);
      a.z = mm;
      red[tid] = a;
    }
    __syncthreads();
  }
  float4 tot = red[0];
  float rm0 = tot.x, rs0 = 1.f / tot.y, rm1 = tot.z, rs1 = 1.f / tot.w;
  __shared__ int ssrc[128];
  __shared__ float sw[128][2];
  int h = tid >> 7;
  float acc = 0.f;
  for (int c0 = start; c0 < end; c0 += 128) {
    int cnt = min(128, end - c0);
    __syncthreads();
    if (tid < cnt) {
      int sn = srcs[c0 + tid];
      ssrc[tid] = sn;
      sw[tid][0] = __expf(leaky(es[sn * 2 + 0] + ed0) - rm0) * rs0;
      sw[tid][1] = __expf(leaky(es[sn * 2 + 1] + ed1) - rm1) * rs1;
    }
    __syncthreads();
    for (int i = 0; i < cnt; ++i)
      acc = fmaf(sw[i][h], b2f(z[(size_t)ssrc[i] * 256 + tid]), acc);
  }
  hout[(size_t)n * 256 + tid] = f2b(fmaxf(acc, 0.f));
}

// ---------------- host ----------------
extern "C" void kernel_launch(void* const* d_in, const int* in_sizes, int n_in,
                              void* d_out, int out_size, void* d_ws, size_t ws_size,
                              hipStream_t stream) {
  const float* in_feat = (const float*)d_in[0];
  const int* srcp = (const int*)d_in[1];
  const int* dstp = (const int*)d_in[2];
  const float* W1 = (const float*)d_in[3];
  const float* as1 = (const float*)d_in[4];
  const float* ad1 = (const float*)d_in[5];
  const float* W2 = (const float*)d_in[6];
  const float* as2 = (const float*)d_in[7];
  const float* ad2 = (const float*)d_in[8];
  const float* wi_f = (const float*)d_in[9];
  const float* wh_f = (const float*)d_in[10];
  const float* bi_f = (const float*)d_in[11];
  const float* bh_f = (const float*)d_in[12];
  const float* wi_b = (const float*)d_in[13];
  const float* wh_b = (const float*)d_in[14];
  const float* bi_b = (const float*)d_in[15];
  const float* bh_b = (const float*)d_in[16];
  // d_in[17] = s_w: dead (softmax over a singleton axis == 1.0)
  const float* lin_w = (const float*)d_in[18];
  (void)in_sizes; (void)n_in; (void)out_size;

  const size_t UNIT = (size_t)MP * 256 * 2;
  char* ws = (char*)d_ws;
  size_t off = 0;
  auto take = [&](size_t bytes) -> void* {
    void* p = ws + off;
    off += (bytes + 255) & ~(size_t)255;
    return p;
  };
  __hip_bfloat16* U0 = (__hip_bfloat16*)take(UNIT);      // x, then T
  __hip_bfloat16* U1 = (__hip_bfloat16*)take(UNIT * 2);  // z (GAT), then RZ (stride 512)
  __hip_bfloat16* h1 = (__hip_bfloat16*)take(UNIT);
  __hip_bfloat16* h2 = (__hip_bfloat16*)take(UNIT);
  __hip_bfloat16* hpF = (__hip_bfloat16*)take(UNIT);     // f0, then f0+f1
  __hip_bfloat16* hpB = (__hip_bfloat16*)take(UNIT);     // b1, then b1+b0
  __hip_bfloat16* wW1 = (__hip_bfloat16*)take(65536 * 2);
  __hip_bfloat16* wW2 = (__hip_bfloat16*)take(65536 * 2);
  __hip_bfloat16* wif = (__hip_bfloat16*)take(196608 * 2);
  __hip_bfloat16* whf = (__hip_bfloat16*)take(196608 * 2);
  __hip_bfloat16* wib = (__hip_bfloat16*)take(196608 * 2);
  __hip_bfloat16* whb = (__hip_bfloat16*)take(196608 * 2);
  __hip_bfloat16* wlinA = (__hip_bfloat16*)take(65536 * 2);
  __hip_bfloat16* wlinB = (__hip_bfloat16*)take(65536 * 2);
  float* es = (float*)take((size_t)NN * 2 * 4);
  float* ed = (float*)take((size_t)NN * 2 * 4);
  int* deg = (int*)take((size_t)NN * 4);
  int* cursor = (int*)take((size_t)NN * 4);
  int* row_ptr = (int*)take((size_t)(NN + 1) * 4);
  int* bsum = (int*)take(256 * 4);
  int* boff = (int*)take(256 * 4);
  int* srcs = (int*)take((size_t)NE * 4);

  if (off > ws_size) {  // diagnostic: report ws_size via absmax instead of faulting
    diag_kernel<<<1, 1, 0, stream>>>((float*)d_out, (float)ws_size);
    return;
  }

  // conversions
  conv_kernel<<<4096, 256, 0, stream>>>(in_feat, U0, NN * 256);
  conv_kernel<<<256, 256, 0, stream>>>(W1, wW1, 65536);
  conv_kernel<<<256, 256, 0, stream>>>(W2, wW2, 65536);
  conv_kernel<<<768, 256, 0, stream>>>(wi_f, wif, 196608);
  conv_kernel<<<768, 256, 0, stream>>>(wh_f, whf, 196608);
  conv_kernel<<<768, 256, 0, stream>>>(wi_b, wib, 196608);
  conv_kernel<<<768, 256, 0, stream>>>(wh_b, whb, 196608);
  conv_strided<<<256, 256, 0, stream>>>(lin_w, wlinA, 256, 256, 512, 0);
  conv_strided<<<256, 256, 0, stream>>>(lin_w, wlinB, 256, 256, 512, 256);

  // CSR by dst
  zero_i32<<<NBLK, 256, 0, stream>>>(deg, NN);
  hist_kernel<<<1024, 256, 0, stream>>>(dstp, deg, NE);
  scan1<<<NBLK, 256, 0, stream>>>(deg, bsum, NN);
  scan2<<<1, 256, 0, stream>>>(bsum, boff, NBLK);
  scan3<<<NBLK, 256, 0, stream>>>(deg, boff, row_ptr, cursor, NN, NE);
  scatter_kernel<<<1024, 256, 0, stream>>>(srcp, dstp, cursor, srcs, NE);

  dim3 g2(2, MP / 128), g4(4, MP / 128);
  const __hip_bfloat16* wifN = wif + 512 * 256;  // Wi_n slice
  const __hip_bfloat16* whfN = whf + 512 * 256;
  const __hip_bfloat16* wibN = wib + 512 * 256;
  const __hip_bfloat16* whbN = whb + 512 * 256;

  // GAT layer 1: z = x@W1^T ; h1 = relu(agg(z))
  gemm256<EPI_BF16, false><<<g2, 256, 0, stream>>>(U0, wW1, nullptr, nullptr, U1, NN, 256,
                                                   nullptr, nullptr, nullptr, nullptr, nullptr);
  esed_kernel<<<NN, 256, 0, stream>>>(U1, as1, ad1, es, ed);
  gat_agg<<<NN, 256, 0, stream>>>(row_ptr, srcs, es, ed, U1, h1);
  // GAT layer 2
  gemm256<EPI_BF16, false><<<g2, 256, 0, stream>>>(h1, wW2, nullptr, nullptr, U1, NN, 256,
                                                   nullptr, nullptr, nullptr, nullptr, nullptr);
  esed_kernel<<<NN, 256, 0, stream>>>(U1, as2, ad2, es, ed);
  gat_agg<<<NN, 256, 0, stream>>>(row_ptr, srcs, es, ed, U1, h2);

  // forward GRU: f0 = step(0, h1); fsum = f0 + step(f0, h2)
  gemm256<EPI_SIGM, false><<<g4, 256, 0, stream>>>(h1, wif, nullptr, nullptr, U1, NN, 512,
                                                   bi_f, bh_f, nullptr, nullptr, nullptr);
  gemm256<EPI_GRUF, false><<<g2, 256, 0, stream>>>(h1, wifN, nullptr, nullptr, nullptr, NN, 256,
                                                   bi_f, bh_f, U1, nullptr, hpF);
  gemm256<EPI_SIGM, true><<<g4, 256, 0, stream>>>(h2, wif, hpF, whf, U1, NN, 512,
                                                  bi_f, bh_f, nullptr, nullptr, nullptr);
  gemm256<EPI_BIAS, false><<<g2, 256, 0, stream>>>(hpF, whfN, nullptr, nullptr, U0, NN, 256,
                                                   nullptr, bh_f, nullptr, nullptr, nullptr);
  gemm256<EPI_GRUS, false><<<g2, 256, 0, stream>>>(h2, wifN, nullptr, nullptr, nullptr, NN, 256,
                                                   bi_f, nullptr, U1, U0, hpF);

  // backward GRU: b1 = step(0, h2); bsum = b1 + step(b1, h1)
  gemm256<EPI_SIGM, false><<<g4, 256, 0, stream>>>(h2, wib, nullptr, nullptr, U1, NN, 512,
                                                   bi_b, bh_b, nullptr, nullptr, nullptr);
  gemm256<EPI_GRUF, false><<<g2, 256, 0, stream>>>(h2, wibN, nullptr, nullptr, nullptr, NN, 256,
                                                   bi_b, bh_b, U1, nullptr, hpB);
  gemm256<EPI_SIGM, true><<<g4, 256, 0, stream>>>(h1, wib, hpB, whb, U1, NN, 512,
                                                  bi_b, bh_b, nullptr, nullptr, nullptr);
  gemm256<EPI_BIAS, false><<<g2, 256, 0, stream>>>(hpB, whbN, nullptr, nullptr, U0, NN, 256,
                                                   nullptr, bh_b, nullptr, nullptr, nullptr);
  gemm256<EPI_GRUS, false><<<g2, 256, 0, stream>>>(h1, wibN, nullptr, nullptr, nullptr, NN, 256,
                                                   bi_b, nullptr, U1, U0, hpB);

  // out = fsum@linA^T + bsum@linB^T
  gemm256<EPI_OUT, true><<<g2, 256, 0, stream>>>(hpF, wlinA, hpB, wlinB, d_out, NN, 256,
                                                 nullptr, nullptr, nullptr, nullptr, nullptr);
}

// Round 3
// 1022.242 us; speedup vs baseline: 1.1139x; 1.1139x over previous
//
#include <hip/hip_runtime.h>
#include <hip/hip_bf16.h>

#define NN 50000
#define NE 800000
#define MP 50048           // 391*128 padded rows
#define NBLK 196           // ceil(NN/256)

typedef __attribute__((ext_vector_type(8))) short short8;
typedef __attribute__((ext_vector_type(4))) float f32x4;

__device__ __forceinline__ float b2f(__hip_bfloat16 x) { return __bfloat162float(x); }
__device__ __forceinline__ __hip_bfloat16 f2b(float x) { return __float2bfloat16(x); }
__device__ __forceinline__ float bu2f(unsigned short u) { return __uint_as_float(((unsigned)u) << 16); }
__device__ __forceinline__ unsigned short f2bu(float x) { __hip_bfloat16 b = f2b(x); return *(unsigned short*)&b; }
__device__ __forceinline__ float sigm(float x) { return 1.f / (1.f + __expf(-x)); }
__device__ __forceinline__ float leaky(float x) { return x >= 0.f ? x : 0.2f * x; }

__device__ __forceinline__ void gload16(const void* g, void* l) {
  __builtin_amdgcn_global_load_lds((__attribute__((address_space(1))) void*)(g),
                                   (__attribute__((address_space(3))) void*)(l), 16, 0, 0);
}

__global__ void diag_kernel(float* out, float v) { out[0] = v; }

__global__ void zero_i32(int* p, int n) {
  int i = blockIdx.x * 256 + threadIdx.x;
  if (i < n) p[i] = 0;
}

__global__ void conv_kernel(const float* __restrict__ in, __hip_bfloat16* __restrict__ out, int n) {
  for (int i = blockIdx.x * blockDim.x + threadIdx.x; i < n; i += gridDim.x * blockDim.x)
    out[i] = f2b(in[i]);
}

// vectorized: 4 floats -> 4 bf16 per thread (n % 4 == 0)
__global__ void conv4_kernel(const float* __restrict__ in, __hip_bfloat16* __restrict__ out, int n4) {
  int i = blockIdx.x * 256 + threadIdx.x;
  if (i >= n4) return;
  float4 v = ((const float4*)in)[i];
  ushort4 o;
  o.x = f2bu(v.x); o.y = f2bu(v.y); o.z = f2bu(v.z); o.w = f2bu(v.w);
  ((ushort4*)out)[i] = o;
}

// 4 GRU weight mats (196608 each) -> contiguous bf16 out
__global__ void conv_gruw(const float* __restrict__ p0, const float* __restrict__ p1,
                          const float* __restrict__ p2, const float* __restrict__ p3,
                          __hip_bfloat16* __restrict__ out) {
  int idx = blockIdx.x * 256 + threadIdx.x;  // 786432 total
  int w = idx / 196608, r = idx - w * 196608;
  const float* s = (w == 0) ? p0 : (w == 1) ? p1 : (w == 2) ? p2 : p3;
  out[idx] = f2b(s[r]);
}

// out[r*cols+c] = in[r*ld + coff + c]
__global__ void conv_strided(const float* __restrict__ in, __hip_bfloat16* __restrict__ out,
                             int rows, int cols, int ld, int coff) {
  int idx = blockIdx.x * 256 + threadIdx.x;
  if (idx >= rows * cols) return;
  int r = idx / cols, c = idx - r * cols;
  out[idx] = f2b(in[(size_t)r * ld + coff + c]);
}

// ---------------- unified GEMM: C = A1*B1^T (+ A2*B2^T), K=256 per pass ----------------
#define EPI_BF16 0
#define EPI_SIGM 1
#define EPI_BIAS 2
#define EPI_GRUF 3
#define EPI_GRUS 4
#define EPI_OUT  5

template <int EPI, bool DUAL>
__global__ __launch_bounds__(256) void gemm256(
    const __hip_bfloat16* __restrict__ A1, const __hip_bfloat16* __restrict__ B1,
    const __hip_bfloat16* __restrict__ A2, const __hip_bfloat16* __restrict__ B2,
    void* __restrict__ Cv, int M, int N,
    const float* __restrict__ bi, const float* __restrict__ bh,
    const __hip_bfloat16* __restrict__ RZ, const __hip_bfloat16* __restrict__ T,
    __hip_bfloat16* __restrict__ HP) {
  __shared__ __align__(16) short smem[8192];  // As[128][32] + Bs[128][32]
  short* As = smem;
  short* Bs = smem + 4096;
  const int tid = threadIdx.x;
  const int wid = tid >> 6, lane = tid & 63;
  const int m0 = blockIdx.y * 128, n0 = blockIdx.x * 128;
  const int wr = wid >> 1, wc = wid & 1;
  const int sr = lane >> 2, kp = (lane & 3) * 8;
  const int lrow = lane & 15, lk = (lane >> 4) * 8;
  f32x4 acc[4][4];
#pragma unroll
  for (int i = 0; i < 4; ++i)
#pragma unroll
    for (int j = 0; j < 4; ++j) acc[i][j] = (f32x4)0.f;

#pragma unroll
  for (int pass = 0; pass < (DUAL ? 2 : 1); ++pass) {
    const __hip_bfloat16* A = pass ? A2 : A1;
    const __hip_bfloat16* B = pass ? B2 : B1;
    for (int k0 = 0; k0 < 256; k0 += 32) {
#pragma unroll
      for (int ss = 0; ss < 2; ++ss) {
        int s = wid + ss * 4;
        gload16(A + (size_t)(m0 + s * 16 + sr) * 256 + k0 + kp, &As[s * 512]);
        gload16(B + (size_t)(n0 + s * 16 + sr) * 256 + k0 + kp, &Bs[s * 512]);
      }
      __syncthreads();
      short8 af[4], bfv[4];
#pragma unroll
      for (int i = 0; i < 4; ++i) af[i] = *(const short8*)&As[(wr * 64 + i * 16 + lrow) * 32 + lk];
#pragma unroll
      for (int j = 0; j < 4; ++j) bfv[j] = *(const short8*)&Bs[(wc * 64 + j * 16 + lrow) * 32 + lk];
#pragma unroll
      for (int i = 0; i < 4; ++i)
#pragma unroll
        for (int j = 0; j < 4; ++j)
          acc[i][j] = __builtin_amdgcn_mfma_f32_16x16x32_bf16(af[i], bfv[j], acc[i][j], 0, 0, 0);
      __syncthreads();
    }
  }

  const int rowb = m0 + wr * 64 + (lane >> 4) * 4;
  const int colb = n0 + wc * 64 + (lane & 15);
#pragma unroll
  for (int i = 0; i < 4; ++i) {
#pragma unroll
    for (int j = 0; j < 4; ++j) {
      const int col = colb + j * 16;
#pragma unroll
      for (int rr = 0; rr < 4; ++rr) {
        const int row = rowb + i * 16 + rr;
        if (row >= M) continue;
        float v = acc[i][j][rr];
        if constexpr (EPI == EPI_BF16) {
          ((__hip_bfloat16*)Cv)[(size_t)row * N + col] = f2b(v);
        } else if constexpr (EPI == EPI_SIGM) {
          ((__hip_bfloat16*)Cv)[(size_t)row * 512 + col] = f2b(sigm(v + bi[col] + bh[col]));
        } else if constexpr (EPI == EPI_BIAS) {
          ((__hip_bfloat16*)Cv)[(size_t)row * 256 + col] = f2b(v + bh[512 + col]);
        } else if constexpr (EPI == EPI_GRUF) {
          float r_ = b2f(RZ[(size_t)row * 512 + col]);
          float z_ = b2f(RZ[(size_t)row * 512 + 256 + col]);
          float n_ = tanhf(v + bi[512 + col] + r_ * bh[512 + col]);
          HP[(size_t)row * 256 + col] = f2b((1.f - z_) * n_);
        } else if constexpr (EPI == EPI_GRUS) {
          float r_ = b2f(RZ[(size_t)row * 512 + col]);
          float z_ = b2f(RZ[(size_t)row * 512 + 256 + col]);
          float t_ = b2f(T[(size_t)row * 256 + col]);          // already + bh_n
          float n_ = tanhf(v + bi[512 + col] + r_ * t_);
          float hp = b2f(HP[(size_t)row * 256 + col]);
          HP[(size_t)row * 256 + col] = f2b(hp + (1.f - z_) * n_ + z_ * hp);
        } else {  // EPI_OUT
          ((float*)Cv)[(size_t)row * 256 + col] = v;
        }
      }
    }
  }
}

// ---------------- attention logits: one wave per node ----------------
__global__ __launch_bounds__(256) void esed_wave(const __hip_bfloat16* __restrict__ z,
                                                 const float* __restrict__ a_s,
                                                 const float* __restrict__ a_d,
                                                 float* __restrict__ es, float* __restrict__ ed) {
  int node = blockIdx.x * 4 + (threadIdx.x >> 6);
  int lane = threadIdx.x & 63;
  if (node >= NN) return;
  ushort4 zv = *(const ushort4*)&z[(size_t)node * 256 + lane * 4];
  int d0 = lane * 4;
  const float* av = a_s + d0;
  const float* dv = a_d + d0;
  float z0 = bu2f(zv.x), z1 = bu2f(zv.y), z2 = bu2f(zv.z), z3 = bu2f(zv.w);
  float pes = z0 * av[0] + z1 * av[1] + z2 * av[2] + z3 * av[3];
  float ped = z0 * dv[0] + z1 * dv[1] + z2 * dv[2] + z3 * dv[3];
#pragma unroll
  for (int off = 16; off > 0; off >>= 1) {   // reduce within 32-lane half (one head each)
    pes += __shfl_xor(pes, off, 64);
    ped += __shfl_xor(ped, off, 64);
  }
  int h = lane >> 5;
  if ((lane & 31) == 0) {
    es[node * 2 + h] = pes;
    ed[node * 2 + h] = ped;
  }
}

// ---------------- CSR build ----------------
__global__ void hist_kernel(const int* __restrict__ dst, int* __restrict__ deg, int ne) {
  for (int e = blockIdx.x * blockDim.x + threadIdx.x; e < ne; e += gridDim.x * blockDim.x)
    atomicAdd(&deg[dst[e]], 1);
}

__global__ void scan1(const int* __restrict__ deg, int* __restrict__ bsum, int n) {
  __shared__ int sd[256];
  int idx = blockIdx.x * 256 + threadIdx.x;
  sd[threadIdx.x] = (idx < n) ? deg[idx] : 0;
  __syncthreads();
  for (int off = 128; off > 0; off >>= 1) {
    if (threadIdx.x < off) sd[threadIdx.x] += sd[threadIdx.x + off];
    __syncthreads();
  }
  if (threadIdx.x == 0) bsum[blockIdx.x] = sd[0];
}

__global__ void scan2(const int* __restrict__ bsum, int* __restrict__ boff, int nb) {
  __shared__ int s[256];
  int t = threadIdx.x;
  int v0 = (t < nb) ? bsum[t] : 0;
  s[t] = v0;
  __syncthreads();
  for (int off = 1; off < 256; off <<= 1) {
    int x = (t >= off) ? s[t - off] : 0;
    __syncthreads();
    s[t] += x;
    __syncthreads();
  }
  if (t < nb) boff[t] = s[t] - v0;
}

__global__ void scan3(const int* __restrict__ deg, const int* __restrict__ boff,
                      int* __restrict__ row_ptr, int* __restrict__ cursor, int n, int ne) {
  __shared__ int s[256];
  int t = threadIdx.x;
  int idx = blockIdx.x * 256 + t;
  int v = (idx < n) ? deg[idx] : 0;
  s[t] = v;
  __syncthreads();
  for (int off = 1; off < 256; off <<= 1) {
    int x = (t >= off) ? s[t - off] : 0;
    __syncthreads();
    s[t] += x;
    __syncthreads();
  }
  if (idx < n) {
    int val = boff[blockIdx.x] + s[t] - v;
    row_ptr[idx] = val;
    cursor[idx] = val;
  }
  if (idx == n) row_ptr[n] = ne;
}

__global__ void scatter_kernel(const int* __restrict__ src, const int* __restrict__ dst,
                               int* __restrict__ cursor, int* __restrict__ srcs, int ne) {
  for (int e = blockIdx.x * blockDim.x + threadIdx.x; e < ne; e += gridDim.x * blockDim.x) {
    int p = atomicAdd(&cursor[dst[e]], 1);
    srcs[p] = src[e];
  }
}

// ---------------- GAT aggregation: one wave per node, ushort4 gathers ----------------
__device__ __forceinline__ void onl_upd(float& m, float& s, float v) {
  if (v <= m) {
    s += __expf(v - m);
  } else {
    s = s * __expf(m - v) + 1.f;
    m = v;
  }
}

__global__ __launch_bounds__(256) void gat_agg_wave(const int* __restrict__ row_ptr,
                                                    const int* __restrict__ srcs,
                                                    const float* __restrict__ es,
                                                    const float* __restrict__ ed,
                                                    const __hip_bfloat16* __restrict__ z,
                                                    __hip_bfloat16* __restrict__ hout) {
  int node = blockIdx.x * 4 + (threadIdx.x >> 6);
  int lane = threadIdx.x & 63;
  if (node >= NN) return;
  ushort4* outp = (ushort4*)&hout[(size_t)node * 256 + lane * 4];
  int start = row_ptr[node], end = row_ptr[node + 1];
  if (start == end) {
    *outp = make_ushort4(0, 0, 0, 0);
    return;
  }
  float ed0 = ed[node * 2], ed1 = ed[node * 2 + 1];
  // phase 1: per-lane online max/sum over this node's edges
  float m0 = -1e30f, s0 = 0.f, m1 = -1e30f, s1 = 0.f;
  for (int i = start + lane; i < end; i += 64) {
    int sn = srcs[i];
    float e0 = es[sn * 2], e1 = es[sn * 2 + 1];
    onl_upd(m0, s0, leaky(e0 + ed0));
    onl_upd(m1, s1, leaky(e1 + ed1));
  }
  // wave butterfly reduce of (m,s) pairs
#pragma unroll
  for (int off = 32; off > 0; off >>= 1) {
    float om0 = __shfl_xor(m0, off, 64), os0 = __shfl_xor(s0, off, 64);
    float om1 = __shfl_xor(m1, off, 64), os1 = __shfl_xor(s1, off, 64);
    float mm = fmaxf(m0, om0);
    s0 = s0 * __expf(m0 - mm) + os0 * __expf(om0 - mm);
    m0 = mm;
    mm = fmaxf(m1, om1);
    s1 = s1 * __expf(m1 - mm) + os1 * __expf(om1 - mm);
    m1 = mm;
  }
  int h = lane >> 5;                      // cols lane*4.. -> head
  float rm = h ? m1 : m0;
  float rsi = 1.f / (h ? s1 : s0);
  float edh = h ? ed1 : ed0;
  float a0 = 0.f, a1 = 0.f, a2 = 0.f, a3 = 0.f;
  for (int e = start; e < end; ++e) {
    int sn = srcs[e];                     // wave-uniform
    float2 ee = *(const float2*)&es[sn * 2];
    float w = __expf(leaky((h ? ee.y : ee.x) + edh) - rm) * rsi;
    ushort4 zv = *(const ushort4*)&z[(size_t)sn * 256 + lane * 4];
    a0 = fmaf(w, bu2f(zv.x), a0);
    a1 = fmaf(w, bu2f(zv.y), a1);
    a2 = fmaf(w, bu2f(zv.z), a2);
    a3 = fmaf(w, bu2f(zv.w), a3);
  }
  ushort4 o;
  o.x = f2bu(fmaxf(a0, 0.f));
  o.y = f2bu(fmaxf(a1, 0.f));
  o.z = f2bu(fmaxf(a2, 0.f));
  o.w = f2bu(fmaxf(a3, 0.f));
  *outp = o;
}

// ---------------- host ----------------
extern "C" void kernel_launch(void* const* d_in, const int* in_sizes, int n_in,
                              void* d_out, int out_size, void* d_ws, size_t ws_size,
                              hipStream_t stream) {
  const float* in_feat = (const float*)d_in[0];
  const int* srcp = (const int*)d_in[1];
  const int* dstp = (const int*)d_in[2];
  const float* W1 = (const float*)d_in[3];
  const float* as1 = (const float*)d_in[4];
  const float* ad1 = (const float*)d_in[5];
  const float* W2 = (const float*)d_in[6];
  const float* as2 = (const float*)d_in[7];
  const float* ad2 = (const float*)d_in[8];
  const float* wi_f = (const float*)d_in[9];
  const float* wh_f = (const float*)d_in[10];
  const float* bi_f = (const float*)d_in[11];
  const float* bh_f = (const float*)d_in[12];
  const float* wi_b = (const float*)d_in[13];
  const float* wh_b = (const float*)d_in[14];
  const float* bi_b = (const float*)d_in[15];
  const float* bh_b = (const float*)d_in[16];
  // d_in[17] = s_w: dead (softmax over a singleton axis == 1.0)
  const float* lin_w = (const float*)d_in[18];
  (void)in_sizes; (void)n_in; (void)out_size;

  const size_t UNIT = (size_t)MP * 256 * 2;
  char* ws = (char*)d_ws;
  size_t off = 0;
  auto take = [&](size_t bytes) -> void* {
    void* p = ws + off;
    off += (bytes + 255) & ~(size_t)255;
    return p;
  };
  __hip_bfloat16* U0 = (__hip_bfloat16*)take(UNIT);      // x, then T
  __hip_bfloat16* U1 = (__hip_bfloat16*)take(UNIT * 2);  // z (GAT), then RZ (stride 512)
  __hip_bfloat16* h1 = (__hip_bfloat16*)take(UNIT);
  __hip_bfloat16* h2 = (__hip_bfloat16*)take(UNIT);
  __hip_bfloat16* hpF = (__hip_bfloat16*)take(UNIT);     // f0, then f0+f1
  __hip_bfloat16* hpB = (__hip_bfloat16*)take(UNIT);     // b1, then b1+b0
  __hip_bfloat16* wW1 = (__hip_bfloat16*)take(65536 * 2);
  __hip_bfloat16* wW2 = (__hip_bfloat16*)take(65536 * 2);
  __hip_bfloat16* wif = (__hip_bfloat16*)take(196608 * 2);  // order matters: conv_gruw writes
  __hip_bfloat16* whf = (__hip_bfloat16*)take(196608 * 2);  // wif,whf,wib,whb contiguously
  __hip_bfloat16* wib = (__hip_bfloat16*)take(196608 * 2);
  __hip_bfloat16* whb = (__hip_bfloat16*)take(196608 * 2);
  __hip_bfloat16* wlinA = (__hip_bfloat16*)take(65536 * 2);
  __hip_bfloat16* wlinB = (__hip_bfloat16*)take(65536 * 2);
  float* es = (float*)take((size_t)NN * 2 * 4);
  float* ed = (float*)take((size_t)NN * 2 * 4);
  int* deg = (int*)take((size_t)NN * 4);
  int* cursor = (int*)take((size_t)NN * 4);
  int* row_ptr = (int*)take((size_t)(NN + 1) * 4);
  int* bsum = (int*)take(256 * 4);
  int* boff = (int*)take(256 * 4);
  int* srcs = (int*)take((size_t)NE * 4);

  if (off > ws_size) {  // diagnostic: report ws_size via absmax instead of faulting
    diag_kernel<<<1, 1, 0, stream>>>((float*)d_out, (float)ws_size);
    return;
  }

  // conversions
  conv4_kernel<<<12500, 256, 0, stream>>>(in_feat, U0, NN * 64);
  conv_kernel<<<256, 256, 0, stream>>>(W1, wW1, 65536);
  conv_kernel<<<256, 256, 0, stream>>>(W2, wW2, 65536);
  conv_gruw<<<3072, 256, 0, stream>>>(wi_f, wh_f, wi_b, wh_b, wif);
  conv_strided<<<256, 256, 0, stream>>>(lin_w, wlinA, 256, 256, 512, 0);
  conv_strided<<<256, 256, 0, stream>>>(lin_w, wlinB, 256, 256, 512, 256);

  // CSR by dst
  zero_i32<<<NBLK, 256, 0, stream>>>(deg, NN);
  hist_kernel<<<1024, 256, 0, stream>>>(dstp, deg, NE);
  scan1<<<NBLK, 256, 0, stream>>>(deg, bsum, NN);
  scan2<<<1, 256, 0, stream>>>(bsum, boff, NBLK);
  scan3<<<NBLK, 256, 0, stream>>>(deg, boff, row_ptr, cursor, NN, NE);
  scatter_kernel<<<1024, 256, 0, stream>>>(srcp, dstp, cursor, srcs, NE);

  dim3 g2(2, MP / 128), g4(4, MP / 128);
  const __hip_bfloat16* wifN = wif + 512 * 256;  // Wi_n slice
  const __hip_bfloat16* whfN = whf + 512 * 256;
  const __hip_bfloat16* wibN = wib + 512 * 256;
  const __hip_bfloat16* whbN = whb + 512 * 256;

  // GAT layer 1: z = x@W1^T ; h1 = relu(agg(z))
  gemm256<EPI_BF16, false><<<g2, 256, 0, stream>>>(U0, wW1, nullptr, nullptr, U1, NN, 256,
                                                   nullptr, nullptr, nullptr, nullptr, nullptr);
  esed_wave<<<12500, 256, 0, stream>>>(U1, as1, ad1, es, ed);
  gat_agg_wave<<<12500, 256, 0, stream>>>(row_ptr, srcs, es, ed, U1, h1);
  // GAT layer 2
  gemm256<EPI_BF16, false><<<g2, 256, 0, stream>>>(h1, wW2, nullptr, nullptr, U1, NN, 256,
                                                   nullptr, nullptr, nullptr, nullptr, nullptr);
  esed_wave<<<12500, 256, 0, stream>>>(U1, as2, ad2, es, ed);
  gat_agg_wave<<<12500, 256, 0, stream>>>(row_ptr, srcs, es, ed, U1, h2);

  // forward GRU: f0 = step(0, h1); fsum = f0 + step(f0, h2)
  gemm256<EPI_SIGM, false><<<g4, 256, 0, stream>>>(h1, wif, nullptr, nullptr, U1, NN, 512,
                                                   bi_f, bh_f, nullptr, nullptr, nullptr);
  gemm256<EPI_GRUF, false><<<g2, 256, 0, stream>>>(h1, wifN, nullptr, nullptr, nullptr, NN, 256,
                                                   bi_f, bh_f, U1, nullptr, hpF);
  gemm256<EPI_SIGM, true><<<g4, 256, 0, stream>>>(h2, wif, hpF, whf, U1, NN, 512,
                                                  bi_f, bh_f, nullptr, nullptr, nullptr);
  gemm256<EPI_BIAS, false><<<g2, 256, 0, stream>>>(hpF, whfN, nullptr, nullptr, U0, NN, 256,
                                                   nullptr, bh_f, nullptr, nullptr, nullptr);
  gemm256<EPI_GRUS, false><<<g2, 256, 0, stream>>>(h2, wifN, nullptr, nullptr, nullptr, NN, 256,
                                                   bi_f, nullptr, U1, U0, hpF);

  // backward GRU: b1 = step(0, h2); bsum = b1 + step(b1, h1)
  gemm256<EPI_SIGM, false><<<g4, 256, 0, stream>>>(h2, wib, nullptr, nullptr, U1, NN, 512,
                                                   bi_b, bh_b, nullptr, nullptr, nullptr);
  gemm256<EPI_GRUF, false><<<g2, 256, 0, stream>>>(h2, wibN, nullptr, nullptr, nullptr, NN, 256,
                                                   bi_b, bh_b, U1, nullptr, hpB);
  gemm256<EPI_SIGM, true><<<g4, 256, 0, stream>>>(h1, wib, hpB, whb, U1, NN, 512,
                                                  bi_b, bh_b, nullptr, nullptr, nullptr);
  gemm256<EPI_BIAS, false><<<g2, 256, 0, stream>>>(hpB, whbN, nullptr, nullptr, U0, NN, 256,
                                                   nullptr, bh_b, nullptr, nullptr, nullptr);
  gemm256<EPI_GRUS, false><<<g2, 256, 0, stream>>>(h1, wibN, nullptr, nullptr, nullptr, NN, 256,
                                                   bi_b, nullptr, U1, U0, hpB);

  // out = fsum@linA^T + bsum@linB^T
  gemm256<EPI_OUT, true><<<g2, 256, 0, stream>>>(hpF, wlinA, hpB, wlinB, d_out, NN, 256,
                                                 nullptr, nullptr, nullptr, nullptr, nullptr);
}

// Round 4
// 1013.315 us; speedup vs baseline: 1.1238x; 1.0088x over previous
//
#include <hip/hip_runtime.h>
#include <hip/hip_bf16.h>

#define NN 50000
#define NE 800000
#define MP 50048           // 391*128 padded rows
#define NBLK 196           // ceil(NN/256)

typedef __attribute__((ext_vector_type(8))) short short8;
typedef __attribute__((ext_vector_type(4))) float f32x4;

__device__ __forceinline__ float b2f(__hip_bfloat16 x) { return __bfloat162float(x); }
__device__ __forceinline__ __hip_bfloat16 f2b(float x) { return __float2bfloat16(x); }
__device__ __forceinline__ float bu2f(unsigned short u) { return __uint_as_float(((unsigned)u) << 16); }
__device__ __forceinline__ unsigned short f2bu(float x) { __hip_bfloat16 b = f2b(x); return *(unsigned short*)&b; }
__device__ __forceinline__ float sigm(float x) { return 1.f / (1.f + __expf(-x)); }
__device__ __forceinline__ float leaky(float x) { return x >= 0.f ? x : 0.2f * x; }

__device__ __forceinline__ void gload16(const void* g, void* l) {
  __builtin_amdgcn_global_load_lds((__attribute__((address_space(1))) void*)(g),
                                   (__attribute__((address_space(3))) void*)(l), 16, 0, 0);
}

__global__ void diag_kernel(float* out, float v) { out[0] = v; }

__global__ void zero_i32(int* p, int n) {
  int i = blockIdx.x * 256 + threadIdx.x;
  if (i < n) p[i] = 0;
}

__global__ void conv_kernel(const float* __restrict__ in, __hip_bfloat16* __restrict__ out, int n) {
  for (int i = blockIdx.x * blockDim.x + threadIdx.x; i < n; i += gridDim.x * blockDim.x)
    out[i] = f2b(in[i]);
}

// vectorized: 4 floats -> 4 bf16 per thread (n % 4 == 0)
__global__ void conv4_kernel(const float* __restrict__ in, __hip_bfloat16* __restrict__ out, int n4) {
  int i = blockIdx.x * 256 + threadIdx.x;
  if (i >= n4) return;
  float4 v = ((const float4*)in)[i];
  ushort4 o;
  o.x = f2bu(v.x); o.y = f2bu(v.y); o.z = f2bu(v.z); o.w = f2bu(v.w);
  ((ushort4*)out)[i] = o;
}

// 4 GRU weight mats (196608 each) -> contiguous bf16 out
__global__ void conv_gruw(const float* __restrict__ p0, const float* __restrict__ p1,
                          const float* __restrict__ p2, const float* __restrict__ p3,
                          __hip_bfloat16* __restrict__ out) {
  int idx = blockIdx.x * 256 + threadIdx.x;  // 786432 total
  int w = idx / 196608, r = idx - w * 196608;
  const float* s = (w == 0) ? p0 : (w == 1) ? p1 : (w == 2) ? p2 : p3;
  out[idx] = f2b(s[r]);
}

// out[r*cols+c] = in[r*ld + coff + c]
__global__ void conv_strided(const float* __restrict__ in, __hip_bfloat16* __restrict__ out,
                             int rows, int cols, int ld, int coff) {
  int idx = blockIdx.x * 256 + threadIdx.x;
  if (idx >= rows * cols) return;
  int r = idx / cols, c = idx - r * cols;
  out[idx] = f2b(in[(size_t)r * ld + coff + c]);
}

// ---------------- unified GEMM: C = A1*B1^T (+ A2*B2^T), K=256 per pass ----------------
// 2-phase double-buffered K-loop: stage(s+1) issued before compute(s), one barrier/step.
#define EPI_BF16 0
#define EPI_SIGM 1
#define EPI_BIAS 2
#define EPI_GRUF 3
#define EPI_GRUS 4
#define EPI_OUT  5
#define EPI_ESED 6

template <int EPI, bool DUAL>
__global__ __launch_bounds__(256) void gemm256(
    const __hip_bfloat16* __restrict__ A1, const __hip_bfloat16* __restrict__ B1,
    const __hip_bfloat16* __restrict__ A2, const __hip_bfloat16* __restrict__ B2,
    void* __restrict__ Cv, int M, int N,
    const float* __restrict__ bi, const float* __restrict__ bh,
    const __hip_bfloat16* __restrict__ RZ, const __hip_bfloat16* __restrict__ T,
    __hip_bfloat16* __restrict__ HP, float* __restrict__ ESp, float* __restrict__ EDp) {
  __shared__ __align__(16) short smem[16384];  // 2 bufs x (As[128][32] + Bs[128][32])
  const int tid = threadIdx.x;
  const int wid = tid >> 6, lane = tid & 63;
  const int m0 = blockIdx.y * 128, n0 = blockIdx.x * 128;
  const int wr = wid >> 1, wc = wid & 1;
  const int sr = lane >> 2, kp = (lane & 3) * 8;
  const int lrow = lane & 15, lk = (lane >> 4) * 8;
  const int NS = DUAL ? 16 : 8;
  f32x4 acc[4][4];
#pragma unroll
  for (int i = 0; i < 4; ++i)
#pragma unroll
    for (int j = 0; j < 4; ++j) acc[i][j] = (f32x4)0.f;

  auto stage = [&](int s, int buf) {
    const __hip_bfloat16* A = (DUAL && s >= 8) ? A2 : A1;
    const __hip_bfloat16* B = (DUAL && s >= 8) ? B2 : B1;
    const int k0 = (s & 7) * 32;
    short* As = smem + buf * 8192;
    short* Bs = As + 4096;
#pragma unroll
    for (int ss = 0; ss < 2; ++ss) {
      int seg = wid + ss * 4;
      gload16(A + (size_t)(m0 + seg * 16 + sr) * 256 + k0 + kp, &As[seg * 512]);
      gload16(B + (size_t)(n0 + seg * 16 + sr) * 256 + k0 + kp, &Bs[seg * 512]);
    }
  };

  stage(0, 0);
  __syncthreads();
  for (int s = 0; s < NS; ++s) {
    const int cur = s & 1;
    if (s + 1 < NS) stage(s + 1, cur ^ 1);
    const short* As = smem + cur * 8192;
    const short* Bs = As + 4096;
    short8 af[4], bfv[4];
#pragma unroll
    for (int i = 0; i < 4; ++i) af[i] = *(const short8*)&As[(wr * 64 + i * 16 + lrow) * 32 + lk];
#pragma unroll
    for (int j = 0; j < 4; ++j) bfv[j] = *(const short8*)&Bs[(wc * 64 + j * 16 + lrow) * 32 + lk];
#pragma unroll
    for (int i = 0; i < 4; ++i)
#pragma unroll
      for (int j = 0; j < 4; ++j)
        acc[i][j] = __builtin_amdgcn_mfma_f32_16x16x32_bf16(af[i], bfv[j], acc[i][j], 0, 0, 0);
    __syncthreads();
  }

  const int rowb = m0 + wr * 64 + (lane >> 4) * 4;
  const int colb = n0 + wc * 64 + (lane & 15);

  if constexpr (EPI == EPI_ESED) {
    // bi = a_s (flat 256), bh = a_d; head fixed per block (n0 in {0,128})
    const int head = n0 >> 7;
#pragma unroll
    for (int i = 0; i < 4; ++i) {
#pragma unroll
      for (int rr = 0; rr < 4; ++rr) {
        const int row = rowb + i * 16 + rr;
        float ps = 0.f, pd = 0.f;
#pragma unroll
        for (int j = 0; j < 4; ++j) {
          const int col = colb + j * 16;
          float v = acc[i][j][rr];
          if (row < M) ((__hip_bfloat16*)Cv)[(size_t)row * N + col] = f2b(v);
          ps += v * bi[col];
          pd += v * bh[col];
        }
#pragma unroll
        for (int o = 8; o >= 1; o >>= 1) {  // reduce across the 16 lanes sharing this row
          ps += __shfl_xor(ps, o, 64);
          pd += __shfl_xor(pd, o, 64);
        }
        if ((lane & 15) == 0 && row < M) {
          atomicAdd(&ESp[row * 2 + head], ps);
          atomicAdd(&EDp[row * 2 + head], pd);
        }
      }
    }
    return;
  }

#pragma unroll
  for (int i = 0; i < 4; ++i) {
#pragma unroll
    for (int j = 0; j < 4; ++j) {
      const int col = colb + j * 16;
#pragma unroll
      for (int rr = 0; rr < 4; ++rr) {
        const int row = rowb + i * 16 + rr;
        if (row >= M) continue;
        float v = acc[i][j][rr];
        if constexpr (EPI == EPI_BF16) {
          ((__hip_bfloat16*)Cv)[(size_t)row * N + col] = f2b(v);
        } else if constexpr (EPI == EPI_SIGM) {
          ((__hip_bfloat16*)Cv)[(size_t)row * 512 + col] = f2b(sigm(v + bi[col] + bh[col]));
        } else if constexpr (EPI == EPI_BIAS) {
          ((__hip_bfloat16*)Cv)[(size_t)row * 256 + col] = f2b(v + bh[512 + col]);
        } else if constexpr (EPI == EPI_GRUF) {
          float r_ = b2f(RZ[(size_t)row * 512 + col]);
          float z_ = b2f(RZ[(size_t)row * 512 + 256 + col]);
          float n_ = tanhf(v + bi[512 + col] + r_ * bh[512 + col]);
          HP[(size_t)row * 256 + col] = f2b((1.f - z_) * n_);
        } else if constexpr (EPI == EPI_GRUS) {
          float r_ = b2f(RZ[(size_t)row * 512 + col]);
          float z_ = b2f(RZ[(size_t)row * 512 + 256 + col]);
          float t_ = b2f(T[(size_t)row * 256 + col]);          // already + bh_n
          float n_ = tanhf(v + bi[512 + col] + r_ * t_);
          float hp = b2f(HP[(size_t)row * 256 + col]);
          HP[(size_t)row * 256 + col] = f2b(hp + (1.f - z_) * n_ + z_ * hp);
        } else {  // EPI_OUT
          ((float*)Cv)[(size_t)row * 256 + col] = v;
        }
      }
    }
  }
}

// ---------------- CSR build ----------------
__global__ void hist_kernel(const int* __restrict__ dst, int* __restrict__ deg, int ne) {
  for (int e = blockIdx.x * blockDim.x + threadIdx.x; e < ne; e += gridDim.x * blockDim.x)
    atomicAdd(&deg[dst[e]], 1);
}

__global__ void scan1(const int* __restrict__ deg, int* __restrict__ bsum, int n) {
  __shared__ int sd[256];
  int idx = blockIdx.x * 256 + threadIdx.x;
  sd[threadIdx.x] = (idx < n) ? deg[idx] : 0;
  __syncthreads();
  for (int off = 128; off > 0; off >>= 1) {
    if (threadIdx.x < off) sd[threadIdx.x] += sd[threadIdx.x + off];
    __syncthreads();
  }
  if (threadIdx.x == 0) bsum[blockIdx.x] = sd[0];
}

__global__ void scan2(const int* __restrict__ bsum, int* __restrict__ boff, int nb) {
  __shared__ int s[256];
  int t = threadIdx.x;
  int v0 = (t < nb) ? bsum[t] : 0;
  s[t] = v0;
  __syncthreads();
  for (int off = 1; off < 256; off <<= 1) {
    int x = (t >= off) ? s[t - off] : 0;
    __syncthreads();
    s[t] += x;
    __syncthreads();
  }
  if (t < nb) boff[t] = s[t] - v0;
}

__global__ void scan3(const int* __restrict__ deg, const int* __restrict__ boff,
                      int* __restrict__ row_ptr, int* __restrict__ cursor, int n, int ne) {
  __shared__ int s[256];
  int t = threadIdx.x;
  int idx = blockIdx.x * 256 + t;
  int v = (idx < n) ? deg[idx] : 0;
  s[t] = v;
  __syncthreads();
  for (int off = 1; off < 256; off <<= 1) {
    int x = (t >= off) ? s[t - off] : 0;
    __syncthreads();
    s[t] += x;
    __syncthreads();
  }
  if (idx < n) {
    int val = boff[blockIdx.x] + s[t] - v;
    row_ptr[idx] = val;
    cursor[idx] = val;
  }
  if (idx == n) row_ptr[n] = ne;
}

__global__ void scatter_kernel(const int* __restrict__ src, const int* __restrict__ dst,
                               int* __restrict__ cursor, int* __restrict__ srcs, int ne) {
  for (int e = blockIdx.x * blockDim.x + threadIdx.x; e < ne; e += gridDim.x * blockDim.x) {
    int p = atomicAdd(&cursor[dst[e]], 1);
    srcs[p] = src[e];
  }
}

// ---------------- GAT aggregation: one wave per node, ushort4 gathers ----------------
__device__ __forceinline__ void onl_upd(float& m, float& s, float v) {
  if (v <= m) {
    s += __expf(v - m);
  } else {
    s = s * __expf(m - v) + 1.f;
    m = v;
  }
}

__global__ __launch_bounds__(256) void gat_agg_wave(const int* __restrict__ row_ptr,
                                                    const int* __restrict__ srcs,
                                                    const float* __restrict__ es,
                                                    const float* __restrict__ ed,
                                                    const __hip_bfloat16* __restrict__ z,
                                                    __hip_bfloat16* __restrict__ hout) {
  int node = blockIdx.x * 4 + (threadIdx.x >> 6);
  int lane = threadIdx.x & 63;
  if (node >= NN) return;
  ushort4* outp = (ushort4*)&hout[(size_t)node * 256 + lane * 4];
  int start = row_ptr[node], end = row_ptr[node + 1];
  if (start == end) {
    *outp = make_ushort4(0, 0, 0, 0);
    return;
  }
  float ed0 = ed[node * 2], ed1 = ed[node * 2 + 1];
  // phase 1: per-lane online max/sum over this node's edges
  float m0 = -1e30f, s0 = 0.f, m1 = -1e30f, s1 = 0.f;
  for (int i = start + lane; i < end; i += 64) {
    int sn = srcs[i];
    float e0 = es[sn * 2], e1 = es[sn * 2 + 1];
    onl_upd(m0, s0, leaky(e0 + ed0));
    onl_upd(m1, s1, leaky(e1 + ed1));
  }
  // wave butterfly reduce of (m,s) pairs
#pragma unroll
  for (int off = 32; off > 0; off >>= 1) {
    float om0 = __shfl_xor(m0, off, 64), os0 = __shfl_xor(s0, off, 64);
    float om1 = __shfl_xor(m1, off, 64), os1 = __shfl_xor(s1, off, 64);
    float mm = fmaxf(m0, om0);
    s0 = s0 * __expf(m0 - mm) + os0 * __expf(om0 - mm);
    m0 = mm;
    mm = fmaxf(m1, om1);
    s1 = s1 * __expf(m1 - mm) + os1 * __expf(om1 - mm);
    m1 = mm;
  }
  int h = lane >> 5;                      // cols lane*4.. -> head
  float rm = h ? m1 : m0;
  float rsi = 1.f / (h ? s1 : s0);
  float edh = h ? ed1 : ed0;
  float a0 = 0.f, a1 = 0.f, a2 = 0.f, a3 = 0.f;
  for (int e = start; e < end; ++e) {
    int sn = srcs[e];                     // wave-uniform
    float2 ee = *(const float2*)&es[sn * 2];
    float w = __expf(leaky((h ? ee.y : ee.x) + edh) - rm) * rsi;
    ushort4 zv = *(const ushort4*)&z[(size_t)sn * 256 + lane * 4];
    a0 = fmaf(w, bu2f(zv.x), a0);
    a1 = fmaf(w, bu2f(zv.y), a1);
    a2 = fmaf(w, bu2f(zv.z), a2);
    a3 = fmaf(w, bu2f(zv.w), a3);
  }
  ushort4 o;
  o.x = f2bu(fmaxf(a0, 0.f));
  o.y = f2bu(fmaxf(a1, 0.f));
  o.z = f2bu(fmaxf(a2, 0.f));
  o.w = f2bu(fmaxf(a3, 0.f));
  *outp = o;
}

// ---------------- host ----------------
extern "C" void kernel_launch(void* const* d_in, const int* in_sizes, int n_in,
                              void* d_out, int out_size, void* d_ws, size_t ws_size,
                              hipStream_t stream) {
  const float* in_feat = (const float*)d_in[0];
  const int* srcp = (const int*)d_in[1];
  const int* dstp = (const int*)d_in[2];
  const float* W1 = (const float*)d_in[3];
  const float* as1 = (const float*)d_in[4];
  const float* ad1 = (const float*)d_in[5];
  const float* W2 = (const float*)d_in[6];
  const float* as2 = (const float*)d_in[7];
  const float* ad2 = (const float*)d_in[8];
  const float* wi_f = (const float*)d_in[9];
  const float* wh_f = (const float*)d_in[10];
  const float* bi_f = (const float*)d_in[11];
  const float* bh_f = (const float*)d_in[12];
  const float* wi_b = (const float*)d_in[13];
  const float* wh_b = (const float*)d_in[14];
  const float* bi_b = (const float*)d_in[15];
  const float* bh_b = (const float*)d_in[16];
  // d_in[17] = s_w: dead (softmax over a singleton axis == 1.0)
  const float* lin_w = (const float*)d_in[18];
  (void)in_sizes; (void)n_in; (void)out_size;

  const size_t UNIT = (size_t)MP * 256 * 2;
  char* ws = (char*)d_ws;
  size_t off = 0;
  auto take = [&](size_t bytes) -> void* {
    void* p = ws + off;
    off += (bytes + 255) & ~(size_t)255;
    return p;
  };
  __hip_bfloat16* U0 = (__hip_bfloat16*)take(UNIT);      // x, then T
  __hip_bfloat16* U1 = (__hip_bfloat16*)take(UNIT * 2);  // z (GAT), then RZ (stride 512)
  __hip_bfloat16* h1 = (__hip_bfloat16*)take(UNIT);
  __hip_bfloat16* h2 = (__hip_bfloat16*)take(UNIT);
  __hip_bfloat16* hpF = (__hip_bfloat16*)take(UNIT);     // f0, then f0+f1
  __hip_bfloat16* hpB = (__hip_bfloat16*)take(UNIT);     // b1, then b1+b0
  __hip_bfloat16* wW1 = (__hip_bfloat16*)take(65536 * 2);
  __hip_bfloat16* wW2 = (__hip_bfloat16*)take(65536 * 2);
  __hip_bfloat16* wif = (__hip_bfloat16*)take(196608 * 2);  // order matters: conv_gruw writes
  __hip_bfloat16* whf = (__hip_bfloat16*)take(196608 * 2);  // wif,whf,wib,whb contiguously
  __hip_bfloat16* wib = (__hip_bfloat16*)take(196608 * 2);
  __hip_bfloat16* whb = (__hip_bfloat16*)take(196608 * 2);
  __hip_bfloat16* wlinA = (__hip_bfloat16*)take(65536 * 2);
  __hip_bfloat16* wlinB = (__hip_bfloat16*)take(65536 * 2);
  // deg..ed2 contiguous, zeroed in one launch
  int* deg = (int*)take((size_t)NN * 4);
  float* es1 = (float*)take((size_t)NN * 2 * 4);
  float* ed1 = (float*)take((size_t)NN * 2 * 4);
  float* es2 = (float*)take((size_t)NN * 2 * 4);
  float* ed2 = (float*)take((size_t)NN * 2 * 4);
  int* cursor = (int*)take((size_t)NN * 4);
  int* row_ptr = (int*)take((size_t)(NN + 1) * 4);
  int* bsum = (int*)take(256 * 4);
  int* boff = (int*)take(256 * 4);
  int* srcs = (int*)take((size_t)NE * 4);

  if (off > ws_size) {  // diagnostic: report ws_size via absmax instead of faulting
    diag_kernel<<<1, 1, 0, stream>>>((float*)d_out, (float)ws_size);
    return;
  }

  // conversions
  conv4_kernel<<<12500, 256, 0, stream>>>(in_feat, U0, NN * 64);
  conv_kernel<<<256, 256, 0, stream>>>(W1, wW1, 65536);
  conv_kernel<<<256, 256, 0, stream>>>(W2, wW2, 65536);
  conv_gruw<<<3072, 256, 0, stream>>>(wi_f, wh_f, wi_b, wh_b, wif);
  conv_strided<<<256, 256, 0, stream>>>(lin_w, wlinA, 256, 256, 512, 0);
  conv_strided<<<256, 256, 0, stream>>>(lin_w, wlinB, 256, 256, 512, 256);

  // zero deg + es/ed (contiguous region)
  {
    int zw = (int)(((char*)ed2 - (char*)deg) / 4) + NN * 2;
    zero_i32<<<(zw + 255) / 256, 256, 0, stream>>>(deg, zw);
  }
  hist_kernel<<<1024, 256, 0, stream>>>(dstp, deg, NE);
  scan1<<<NBLK, 256, 0, stream>>>(deg, bsum, NN);
  scan2<<<1, 256, 0, stream>>>(bsum, boff, NBLK);
  scan3<<<NBLK, 256, 0, stream>>>(deg, boff, row_ptr, cursor, NN, NE);
  scatter_kernel<<<1024, 256, 0, stream>>>(srcp, dstp, cursor, srcs, NE);

  dim3 g2(2, MP / 128), g4(4, MP / 128);
  const __hip_bfloat16* wifN = wif + 512 * 256;  // Wi_n slice
  const __hip_bfloat16* whfN = whf + 512 * 256;
  const __hip_bfloat16* wibN = wib + 512 * 256;
  const __hip_bfloat16* whbN = whb + 512 * 256;

  // GAT layer 1: z = x@W1^T (+ fused es/ed); h1 = relu(agg(z))
  gemm256<EPI_ESED, false><<<g2, 256, 0, stream>>>(U0, wW1, nullptr, nullptr, U1, NN, 256,
                                                   as1, ad1, nullptr, nullptr, nullptr, es1, ed1);
  gat_agg_wave<<<12500, 256, 0, stream>>>(row_ptr, srcs, es1, ed1, U1, h1);
  // GAT layer 2
  gemm256<EPI_ESED, false><<<g2, 256, 0, stream>>>(h1, wW2, nullptr, nullptr, U1, NN, 256,
                                                   as2, ad2, nullptr, nullptr, nullptr, es2, ed2);
  gat_agg_wave<<<12500, 256, 0, stream>>>(row_ptr, srcs, es2, ed2, U1, h2);

  // forward GRU: f0 = step(0, h1); fsum = f0 + step(f0, h2)
  gemm256<EPI_SIGM, false><<<g4, 256, 0, stream>>>(h1, wif, nullptr, nullptr, U1, NN, 512,
                                                   bi_f, bh_f, nullptr, nullptr, nullptr, nullptr, nullptr);
  gemm256<EPI_GRUF, false><<<g2, 256, 0, stream>>>(h1, wifN, nullptr, nullptr, nullptr, NN, 256,
                                                   bi_f, bh_f, U1, nullptr, hpF, nullptr, nullptr);
  gemm256<EPI_SIGM, true><<<g4, 256, 0, stream>>>(h2, wif, hpF, whf, U1, NN, 512,
                                                  bi_f, bh_f, nullptr, nullptr, nullptr, nullptr, nullptr);
  gemm256<EPI_BIAS, false><<<g2, 256, 0, stream>>>(hpF, whfN, nullptr, nullptr, U0, NN, 256,
                                                   nullptr, bh_f, nullptr, nullptr, nullptr, nullptr, nullptr);
  gemm256<EPI_GRUS, false><<<g2, 256, 0, stream>>>(h2, wifN, nullptr, nullptr, nullptr, NN, 256,
                                                   bi_f, nullptr, U1, U0, hpF, nullptr, nullptr);

  // backward GRU: b1 = step(0, h2); bsum = b1 + step(b1, h1)
  gemm256<EPI_SIGM, false><<<g4, 256, 0, stream>>>(h2, wib, nullptr, nullptr, U1, NN, 512,
                                                   bi_b, bh_b, nullptr, nullptr, nullptr, nullptr, nullptr);
  gemm256<EPI_GRUF, false><<<g2, 256, 0, stream>>>(h2, wibN, nullptr, nullptr, nullptr, NN, 256,
                                                   bi_b, bh_b, U1, nullptr, hpB, nullptr, nullptr);
  gemm256<EPI_SIGM, true><<<g4, 256, 0, stream>>>(h1, wib, hpB, whb, U1, NN, 512,
                                                  bi_b, bh_b, nullptr, nullptr, nullptr, nullptr, nullptr);
  gemm256<EPI_BIAS, false><<<g2, 256, 0, stream>>>(hpB, whbN, nullptr, nullptr, U0, NN, 256,
                                                   nullptr, bh_b, nullptr, nullptr, nullptr, nullptr, nullptr);
  gemm256<EPI_GRUS, false><<<g2, 256, 0, stream>>>(h1, wibN, nullptr, nullptr, nullptr, NN, 256,
                                                   bi_b, nullptr, U1, U0, hpB, nullptr, nullptr);

  // out = fsum@linA^T + bsum@linB^T
  gemm256<EPI_OUT, true><<<g2, 256, 0, stream>>>(hpF, wlinA, hpB, wlinB, d_out, NN, 256,
                                                 nullptr, nullptr, nullptr, nullptr, nullptr, nullptr, nullptr);
}

// Round 5
// 999.437 us; speedup vs baseline: 1.1394x; 1.0139x over previous
//
#include <hip/hip_runtime.h>
#include <hip/hip_bf16.h>

#define NN 50000
#define NE 800000
#define MP 50048           // 391*128 padded rows
#define NBLK 196           // ceil(NN/256)

typedef __attribute__((ext_vector_type(8))) short short8;
typedef __attribute__((ext_vector_type(4))) float f32x4;

__device__ __forceinline__ float b2f(__hip_bfloat16 x) { return __bfloat162float(x); }
__device__ __forceinline__ __hip_bfloat16 f2b(float x) { return __float2bfloat16(x); }
__device__ __forceinline__ float bu2f(unsigned short u) { return __uint_as_float(((unsigned)u) << 16); }
__device__ __forceinline__ unsigned short f2bu(float x) { __hip_bfloat16 b = f2b(x); return *(unsigned short*)&b; }
__device__ __forceinline__ float sigm(float x) { return 1.f / (1.f + __expf(-x)); }
__device__ __forceinline__ float leaky(float x) { return x >= 0.f ? x : 0.2f * x; }

__device__ __forceinline__ void gload16(const void* g, void* l) {
  __builtin_amdgcn_global_load_lds((__attribute__((address_space(1))) void*)(g),
                                   (__attribute__((address_space(3))) void*)(l), 16, 0, 0);
}

__global__ void diag_kernel(float* out, float v) { out[0] = v; }

__global__ void zero_i32(int* p, int n) {
  int i = blockIdx.x * 256 + threadIdx.x;
  if (i < n) p[i] = 0;
}

__global__ void conv_kernel(const float* __restrict__ in, __hip_bfloat16* __restrict__ out, int n) {
  for (int i = blockIdx.x * blockDim.x + threadIdx.x; i < n; i += gridDim.x * blockDim.x)
    out[i] = f2b(in[i]);
}

// vectorized: 4 floats -> 4 bf16 per thread (n % 4 == 0)
__global__ void conv4_kernel(const float* __restrict__ in, __hip_bfloat16* __restrict__ out, int n4) {
  int i = blockIdx.x * 256 + threadIdx.x;
  if (i >= n4) return;
  float4 v = ((const float4*)in)[i];
  ushort4 o;
  o.x = f2bu(v.x); o.y = f2bu(v.y); o.z = f2bu(v.z); o.w = f2bu(v.w);
  ((ushort4*)out)[i] = o;
}

// 4 GRU weight mats (196608 each) -> contiguous bf16 out
__global__ void conv_gruw(const float* __restrict__ p0, const float* __restrict__ p1,
                          const float* __restrict__ p2, const float* __restrict__ p3,
                          __hip_bfloat16* __restrict__ out) {
  int idx = blockIdx.x * 256 + threadIdx.x;  // 786432 total
  int w = idx / 196608, r = idx - w * 196608;
  const float* s = (w == 0) ? p0 : (w == 1) ? p1 : (w == 2) ? p2 : p3;
  out[idx] = f2b(s[r]);
}

// out[r*cols+c] = in[r*ld + coff + c]
__global__ void conv_strided(const float* __restrict__ in, __hip_bfloat16* __restrict__ out,
                             int rows, int cols, int ld, int coff) {
  int idx = blockIdx.x * 256 + threadIdx.x;
  if (idx >= rows * cols) return;
  int r = idx / cols, c = idx - r * cols;
  out[idx] = f2b(in[(size_t)r * ld + coff + c]);
}

// ---------------- unified GEMM: C = A1*B1^T (+ A2*B2^T), K=256 per pass ----------------
// Double-buffered K-loop with COUNTED vmcnt (T4): loads for tile s+1 stay in flight
// across the barrier; never drain vmcnt to 0 in the main loop.
#define EPI_BF16 0
#define EPI_SIGM 1
#define EPI_BIAS 2
#define EPI_GRUF 3
#define EPI_GRUS 4
#define EPI_OUT  5
#define EPI_ESED 6

template <int EPI, bool DUAL>
__global__ __launch_bounds__(256) void gemm256(
    const __hip_bfloat16* __restrict__ A1, const __hip_bfloat16* __restrict__ B1,
    const __hip_bfloat16* __restrict__ A2, const __hip_bfloat16* __restrict__ B2,
    void* __restrict__ Cv, int M, int N,
    const float* __restrict__ bi, const float* __restrict__ bh,
    const __hip_bfloat16* __restrict__ RZ, const __hip_bfloat16* __restrict__ T,
    __hip_bfloat16* __restrict__ HP, float* __restrict__ ESp, float* __restrict__ EDp) {
  __shared__ __align__(16) short smem[16384];  // 2 bufs x (As[128][32] + Bs[128][32])
  const int tid = threadIdx.x;
  const int wid = tid >> 6, lane = tid & 63;
  const int m0 = blockIdx.y * 128, n0 = blockIdx.x * 128;
  const int wr = wid >> 1, wc = wid & 1;
  const int sr = lane >> 2, kp = (lane & 3) * 8;
  const int lrow = lane & 15, lk = (lane >> 4) * 8;
  const int NS = DUAL ? 16 : 8;
  f32x4 acc[4][4];
#pragma unroll
  for (int i = 0; i < 4; ++i)
#pragma unroll
    for (int j = 0; j < 4; ++j) acc[i][j] = (f32x4)0.f;

  auto stage = [&](int s, int buf) {
    const __hip_bfloat16* A = (DUAL && s >= 8) ? A2 : A1;
    const __hip_bfloat16* B = (DUAL && s >= 8) ? B2 : B1;
    const int k0 = (s & 7) * 32;
    short* As = smem + buf * 8192;
    short* Bs = As + 4096;
#pragma unroll
    for (int ss = 0; ss < 2; ++ss) {
      int seg = wid + ss * 4;
      gload16(A + (size_t)(m0 + seg * 16 + sr) * 256 + k0 + kp, &As[seg * 512]);
      gload16(B + (size_t)(n0 + seg * 16 + sr) * 256 + k0 + kp, &Bs[seg * 512]);
    }
  };

  auto compute = [&](int s) {
    const short* As = smem + (s & 1) * 8192;
    const short* Bs = As + 4096;
    short8 af[4], bfv[4];
#pragma unroll
    for (int i = 0; i < 4; ++i) af[i] = *(const short8*)&As[(wr * 64 + i * 16 + lrow) * 32 + lk];
#pragma unroll
    for (int j = 0; j < 4; ++j) bfv[j] = *(const short8*)&Bs[(wc * 64 + j * 16 + lrow) * 32 + lk];
#pragma unroll
    for (int i = 0; i < 4; ++i)
#pragma unroll
      for (int j = 0; j < 4; ++j)
        acc[i][j] = __builtin_amdgcn_mfma_f32_16x16x32_bf16(af[i], bfv[j], acc[i][j], 0, 0, 0);
  };

  stage(0, 0);
  stage(1, 1);
  for (int s = 0; s < NS - 1; ++s) {
    // wait for tile s only: tile s+1's 4 loads may remain in flight (per-wave FIFO retire)
    asm volatile("s_waitcnt vmcnt(4)" ::: "memory");
    __builtin_amdgcn_s_barrier();
    __builtin_amdgcn_sched_barrier(0);
    compute(s);
    // all this wave's LDS reads done before anyone overwrites buf[s&1]
    asm volatile("s_waitcnt lgkmcnt(0)" ::: "memory");
    __builtin_amdgcn_sched_barrier(0);
    __builtin_amdgcn_s_barrier();
    if (s + 2 < NS) stage(s + 2, s & 1);
  }
  asm volatile("s_waitcnt vmcnt(0)" ::: "memory");
  __builtin_amdgcn_s_barrier();
  __builtin_amdgcn_sched_barrier(0);
  compute(NS - 1);

  const int rowb = m0 + wr * 64 + (lane >> 4) * 4;
  const int colb = n0 + wc * 64 + (lane & 15);

  if constexpr (EPI == EPI_ESED) {
    // bi = a_s (flat 256), bh = a_d; head fixed per block (n0 in {0,128})
    const int head = n0 >> 7;
#pragma unroll
    for (int i = 0; i < 4; ++i) {
#pragma unroll
      for (int rr = 0; rr < 4; ++rr) {
        const int row = rowb + i * 16 + rr;
        float ps = 0.f, pd = 0.f;
#pragma unroll
        for (int j = 0; j < 4; ++j) {
          const int col = colb + j * 16;
          float v = acc[i][j][rr];
          if (row < M) ((__hip_bfloat16*)Cv)[(size_t)row * N + col] = f2b(v);
          ps += v * bi[col];
          pd += v * bh[col];
        }
#pragma unroll
        for (int o = 8; o >= 1; o >>= 1) {  // reduce across the 16 lanes sharing this row
          ps += __shfl_xor(ps, o, 64);
          pd += __shfl_xor(pd, o, 64);
        }
        if ((lane & 15) == 0 && row < M) {
          atomicAdd(&ESp[row * 2 + head], ps);
          atomicAdd(&EDp[row * 2 + head], pd);
        }
      }
    }
    return;
  }

#pragma unroll
  for (int i = 0; i < 4; ++i) {
#pragma unroll
    for (int j = 0; j < 4; ++j) {
      const int col = colb + j * 16;
#pragma unroll
      for (int rr = 0; rr < 4; ++rr) {
        const int row = rowb + i * 16 + rr;
        if (row >= M) continue;
        float v = acc[i][j][rr];
        if constexpr (EPI == EPI_BF16) {
          ((__hip_bfloat16*)Cv)[(size_t)row * N + col] = f2b(v);
        } else if constexpr (EPI == EPI_SIGM) {
          ((__hip_bfloat16*)Cv)[(size_t)row * 512 + col] = f2b(sigm(v + bi[col] + bh[col]));
        } else if constexpr (EPI == EPI_BIAS) {
          ((__hip_bfloat16*)Cv)[(size_t)row * 256 + col] = f2b(v + bh[512 + col]);
        } else if constexpr (EPI == EPI_GRUF) {
          float r_ = b2f(RZ[(size_t)row * 512 + col]);
          float z_ = b2f(RZ[(size_t)row * 512 + 256 + col]);
          float n_ = tanhf(v + bi[512 + col] + r_ * bh[512 + col]);
          HP[(size_t)row * 256 + col] = f2b((1.f - z_) * n_);
        } else if constexpr (EPI == EPI_GRUS) {
          float r_ = b2f(RZ[(size_t)row * 512 + col]);
          float z_ = b2f(RZ[(size_t)row * 512 + 256 + col]);
          float t_ = b2f(T[(size_t)row * 256 + col]);          // already + bh_n
          float n_ = tanhf(v + bi[512 + col] + r_ * t_);
          float hp = b2f(HP[(size_t)row * 256 + col]);
          HP[(size_t)row * 256 + col] = f2b(hp + (1.f - z_) * n_ + z_ * hp);
        } else {  // EPI_OUT
          ((float*)Cv)[(size_t)row * 256 + col] = v;
        }
      }
    }
  }
}

// ---------------- CSR build ----------------
__global__ void hist_kernel(const int* __restrict__ dst, int* __restrict__ deg, int ne) {
  for (int e = blockIdx.x * blockDim.x + threadIdx.x; e < ne; e += gridDim.x * blockDim.x)
    atomicAdd(&deg[dst[e]], 1);
}

__global__ void scan1(const int* __restrict__ deg, int* __restrict__ bsum, int n) {
  __shared__ int sd[256];
  int idx = blockIdx.x * 256 + threadIdx.x;
  sd[threadIdx.x] = (idx < n) ? deg[idx] : 0;
  __syncthreads();
  for (int off = 128; off > 0; off >>= 1) {
    if (threadIdx.x < off) sd[threadIdx.x] += sd[threadIdx.x + off];
    __syncthreads();
  }
  if (threadIdx.x == 0) bsum[blockIdx.x] = sd[0];
}

__global__ void scan2(const int* __restrict__ bsum, int* __restrict__ boff, int nb) {
  __shared__ int s[256];
  int t = threadIdx.x;
  int v0 = (t < nb) ? bsum[t] : 0;
  s[t] = v0;
  __syncthreads();
  for (int off = 1; off < 256; off <<= 1) {
    int x = (t >= off) ? s[t - off] : 0;
    __syncthreads();
    s[t] += x;
    __syncthreads();
  }
  if (t < nb) boff[t] = s[t] - v0;
}

__global__ void scan3(const int* __restrict__ deg, const int* __restrict__ boff,
                      int* __restrict__ row_ptr, int* __restrict__ cursor, int n, int ne) {
  __shared__ int s[256];
  int t = threadIdx.x;
  int idx = blockIdx.x * 256 + t;
  int v = (idx < n) ? deg[idx] : 0;
  s[t] = v;
  __syncthreads();
  for (int off = 1; off < 256; off <<= 1) {
    int x = (t >= off) ? s[t - off] : 0;
    __syncthreads();
    s[t] += x;
    __syncthreads();
  }
  if (idx < n) {
    int val = boff[blockIdx.x] + s[t] - v;
    row_ptr[idx] = val;
    cursor[idx] = val;
  }
  if (idx == n) row_ptr[n] = ne;
}

__global__ void scatter_kernel(const int* __restrict__ src, const int* __restrict__ dst,
                               int* __restrict__ cursor, int* __restrict__ srcs, int ne) {
  for (int e = blockIdx.x * blockDim.x + threadIdx.x; e < ne; e += gridDim.x * blockDim.x) {
    int p = atomicAdd(&cursor[dst[e]], 1);
    srcs[p] = src[e];
  }
}

// ---------------- GAT aggregation: one wave per node, ushort4 gathers ----------------
__device__ __forceinline__ void onl_upd(float& m, float& s, float v) {
  if (v <= m) {
    s += __expf(v - m);
  } else {
    s = s * __expf(m - v) + 1.f;
    m = v;
  }
}

__global__ __launch_bounds__(256) void gat_agg_wave(const int* __restrict__ row_ptr,
                                                    const int* __restrict__ srcs,
                                                    const float* __restrict__ es,
                                                    const float* __restrict__ ed,
                                                    const __hip_bfloat16* __restrict__ z,
                                                    __hip_bfloat16* __restrict__ hout) {
  int node = blockIdx.x * 4 + (threadIdx.x >> 6);
  int lane = threadIdx.x & 63;
  if (node >= NN) return;
  ushort4* outp = (ushort4*)&hout[(size_t)node * 256 + lane * 4];
  int start = row_ptr[node], end = row_ptr[node + 1];
  if (start == end) {
    *outp = make_ushort4(0, 0, 0, 0);
    return;
  }
  float ed0 = ed[node * 2], ed1 = ed[node * 2 + 1];
  // phase 1: per-lane online max/sum over this node's edges
  float m0 = -1e30f, s0 = 0.f, m1 = -1e30f, s1 = 0.f;
  for (int i = start + lane; i < end; i += 64) {
    int sn = srcs[i];
    float e0 = es[sn * 2], e1 = es[sn * 2 + 1];
    onl_upd(m0, s0, leaky(e0 + ed0));
    onl_upd(m1, s1, leaky(e1 + ed1));
  }
  // wave butterfly reduce of (m,s) pairs
#pragma unroll
  for (int off = 32; off > 0; off >>= 1) {
    float om0 = __shfl_xor(m0, off, 64), os0 = __shfl_xor(s0, off, 64);
    float om1 = __shfl_xor(m1, off, 64), os1 = __shfl_xor(s1, off, 64);
    float mm = fmaxf(m0, om0);
    s0 = s0 * __expf(m0 - mm) + os0 * __expf(om0 - mm);
    m0 = mm;
    mm = fmaxf(m1, om1);
    s1 = s1 * __expf(m1 - mm) + os1 * __expf(om1 - mm);
    m1 = mm;
  }
  int h = lane >> 5;                      // cols lane*4.. -> head
  float rm = h ? m1 : m0;
  float rsi = 1.f / (h ? s1 : s0);
  float edh = h ? ed1 : ed0;
  float a0 = 0.f, a1 = 0.f, a2 = 0.f, a3 = 0.f;
  for (int e = start; e < end; ++e) {
    int sn = srcs[e];                     // wave-uniform
    float2 ee = *(const float2*)&es[sn * 2];
    float w = __expf(leaky((h ? ee.y : ee.x) + edh) - rm) * rsi;
    ushort4 zv = *(const ushort4*)&z[(size_t)sn * 256 + lane * 4];
    a0 = fmaf(w, bu2f(zv.x), a0);
    a1 = fmaf(w, bu2f(zv.y), a1);
    a2 = fmaf(w, bu2f(zv.z), a2);
    a3 = fmaf(w, bu2f(zv.w), a3);
  }
  ushort4 o;
  o.x = f2bu(fmaxf(a0, 0.f));
  o.y = f2bu(fmaxf(a1, 0.f));
  o.z = f2bu(fmaxf(a2, 0.f));
  o.w = f2bu(fmaxf(a3, 0.f));
  *outp = o;
}

// ---------------- host ----------------
extern "C" void kernel_launch(void* const* d_in, const int* in_sizes, int n_in,
                              void* d_out, int out_size, void* d_ws, size_t ws_size,
                              hipStream_t stream) {
  const float* in_feat = (const float*)d_in[0];
  const int* srcp = (const int*)d_in[1];
  const int* dstp = (const int*)d_in[2];
  const float* W1 = (const float*)d_in[3];
  const float* as1 = (const float*)d_in[4];
  const float* ad1 = (const float*)d_in[5];
  const float* W2 = (const float*)d_in[6];
  const float* as2 = (const float*)d_in[7];
  const float* ad2 = (const float*)d_in[8];
  const float* wi_f = (const float*)d_in[9];
  const float* wh_f = (const float*)d_in[10];
  const float* bi_f = (const float*)d_in[11];
  const float* bh_f = (const float*)d_in[12];
  const float* wi_b = (const float*)d_in[13];
  const float* wh_b = (const float*)d_in[14];
  const float* bi_b = (const float*)d_in[15];
  const float* bh_b = (const float*)d_in[16];
  // d_in[17] = s_w: dead (softmax over a singleton axis == 1.0)
  const float* lin_w = (const float*)d_in[18];
  (void)in_sizes; (void)n_in; (void)out_size;

  const size_t UNIT = (size_t)MP * 256 * 2;
  char* ws = (char*)d_ws;
  size_t off = 0;
  auto take = [&](size_t bytes) -> void* {
    void* p = ws + off;
    off += (bytes + 255) & ~(size_t)255;
    return p;
  };
  __hip_bfloat16* U0 = (__hip_bfloat16*)take(UNIT);      // x, then T
  __hip_bfloat16* U1 = (__hip_bfloat16*)take(UNIT * 2);  // z (GAT), then RZ (stride 512)
  __hip_bfloat16* h1 = (__hip_bfloat16*)take(UNIT);
  __hip_bfloat16* h2 = (__hip_bfloat16*)take(UNIT);
  __hip_bfloat16* hpF = (__hip_bfloat16*)take(UNIT);     // f0, then f0+f1
  __hip_bfloat16* hpB = (__hip_bfloat16*)take(UNIT);     // b1, then b1+b0
  __hip_bfloat16* wW1 = (__hip_bfloat16*)take(65536 * 2);
  __hip_bfloat16* wW2 = (__hip_bfloat16*)take(65536 * 2);
  __hip_bfloat16* wif = (__hip_bfloat16*)take(196608 * 2);  // order matters: conv_gruw writes
  __hip_bfloat16* whf = (__hip_bfloat16*)take(196608 * 2);  // wif,whf,wib,whb contiguously
  __hip_bfloat16* wib = (__hip_bfloat16*)take(196608 * 2);
  __hip_bfloat16* whb = (__hip_bfloat16*)take(196608 * 2);
  __hip_bfloat16* wlinA = (__hip_bfloat16*)take(65536 * 2);
  __hip_bfloat16* wlinB = (__hip_bfloat16*)take(65536 * 2);
  // deg..ed2 contiguous, zeroed in one launch
  int* deg = (int*)take((size_t)NN * 4);
  float* es1 = (float*)take((size_t)NN * 2 * 4);
  float* ed1 = (float*)take((size_t)NN * 2 * 4);
  float* es2 = (float*)take((size_t)NN * 2 * 4);
  float* ed2 = (float*)take((size_t)NN * 2 * 4);
  int* cursor = (int*)take((size_t)NN * 4);
  int* row_ptr = (int*)take((size_t)(NN + 1) * 4);
  int* bsum = (int*)take(256 * 4);
  int* boff = (int*)take(256 * 4);
  int* srcs = (int*)take((size_t)NE * 4);

  if (off > ws_size) {  // diagnostic: report ws_size via absmax instead of faulting
    diag_kernel<<<1, 1, 0, stream>>>((float*)d_out, (float)ws_size);
    return;
  }

  // conversions
  conv4_kernel<<<12500, 256, 0, stream>>>(in_feat, U0, NN * 64);
  conv_kernel<<<256, 256, 0, stream>>>(W1, wW1, 65536);
  conv_kernel<<<256, 256, 0, stream>>>(W2, wW2, 65536);
  conv_gruw<<<3072, 256, 0, stream>>>(wi_f, wh_f, wi_b, wh_b, wif);
  conv_strided<<<256, 256, 0, stream>>>(lin_w, wlinA, 256, 256, 512, 0);
  conv_strided<<<256, 256, 0, stream>>>(lin_w, wlinB, 256, 256, 512, 256);

  // zero deg + es/ed (contiguous region)
  {
    int zw = (int)(((char*)ed2 - (char*)deg) / 4) + NN * 2;
    zero_i32<<<(zw + 255) / 256, 256, 0, stream>>>(deg, zw);
  }
  hist_kernel<<<1024, 256, 0, stream>>>(dstp, deg, NE);
  scan1<<<NBLK, 256, 0, stream>>>(deg, bsum, NN);
  scan2<<<1, 256, 0, stream>>>(bsum, boff, NBLK);
  scan3<<<NBLK, 256, 0, stream>>>(deg, boff, row_ptr, cursor, NN, NE);
  scatter_kernel<<<1024, 256, 0, stream>>>(srcp, dstp, cursor, srcs, NE);

  dim3 g2(2, MP / 128), g4(4, MP / 128);
  const __hip_bfloat16* wifN = wif + 512 * 256;  // Wi_n slice
  const __hip_bfloat16* whfN = whf + 512 * 256;
  const __hip_bfloat16* wibN = wib + 512 * 256;
  const __hip_bfloat16* whbN = whb + 512 * 256;

  // GAT layer 1: z = x@W1^T (+ fused es/ed); h1 = relu(agg(z))
  gemm256<EPI_ESED, false><<<g2, 256, 0, stream>>>(U0, wW1, nullptr, nullptr, U1, NN, 256,
                                                   as1, ad1, nullptr, nullptr, nullptr, es1, ed1);
  gat_agg_wave<<<12500, 256, 0, stream>>>(row_ptr, srcs, es1, ed1, U1, h1);
  // GAT layer 2
  gemm256<EPI_ESED, false><<<g2, 256, 0, stream>>>(h1, wW2, nullptr, nullptr, U1, NN, 256,
                                                   as2, ad2, nullptr, nullptr, nullptr, es2, ed2);
  gat_agg_wave<<<12500, 256, 0, stream>>>(row_ptr, srcs, es2, ed2, U1, h2);

  // forward GRU: f0 = step(0, h1); fsum = f0 + step(f0, h2)
  gemm256<EPI_SIGM, false><<<g4, 256, 0, stream>>>(h1, wif, nullptr, nullptr, U1, NN, 512,
                                                   bi_f, bh_f, nullptr, nullptr, nullptr, nullptr, nullptr);
  gemm256<EPI_GRUF, false><<<g2, 256, 0, stream>>>(h1, wifN, nullptr, nullptr, nullptr, NN, 256,
                                                   bi_f, bh_f, U1, nullptr, hpF, nullptr, nullptr);
  gemm256<EPI_SIGM, true><<<g4, 256, 0, stream>>>(h2, wif, hpF, whf, U1, NN, 512,
                                                  bi_f, bh_f, nullptr, nullptr, nullptr, nullptr, nullptr);
  gemm256<EPI_BIAS, false><<<g2, 256, 0, stream>>>(hpF, whfN, nullptr, nullptr, U0, NN, 256,
                                                   nullptr, bh_f, nullptr, nullptr, nullptr, nullptr, nullptr);
  gemm256<EPI_GRUS, false><<<g2, 256, 0, stream>>>(h2, wifN, nullptr, nullptr, nullptr, NN, 256,
                                                   bi_f, nullptr, U1, U0, hpF, nullptr, nullptr);

  // backward GRU: b1 = step(0, h2); bsum = b1 + step(b1, h1)
  gemm256<EPI_SIGM, false><<<g4, 256, 0, stream>>>(h2, wib, nullptr, nullptr, U1, NN, 512,
                                                   bi_b, bh_b, nullptr, nullptr, nullptr, nullptr, nullptr);
  gemm256<EPI_GRUF, false><<<g2, 256, 0, stream>>>(h2, wibN, nullptr, nullptr, nullptr, NN, 256,
                                                   bi_b, bh_b, U1, nullptr, hpB, nullptr, nullptr);
  gemm256<EPI_SIGM, true><<<g4, 256, 0, stream>>>(h1, wib, hpB, whb, U1, NN, 512,
                                                  bi_b, bh_b, nullptr, nullptr, nullptr, nullptr, nullptr);
  gemm256<EPI_BIAS, false><<<g2, 256, 0, stream>>>(hpB, whbN, nullptr, nullptr, U0, NN, 256,
                                                   nullptr, bh_b, nullptr, nullptr, nullptr, nullptr, nullptr);
  gemm256<EPI_GRUS, false><<<g2, 256, 0, stream>>>(h1, wibN, nullptr, nullptr, nullptr, NN, 256,
                                                   bi_b, nullptr, U1, U0, hpB, nullptr, nullptr);

  // out = fsum@linA^T + bsum@linB^T
  gemm256<EPI_OUT, true><<<g2, 256, 0, stream>>>(hpF, wlinA, hpB, wlinB, d_out, NN, 256,
                                                 nullptr, nullptr, nullptr, nullptr, nullptr, nullptr, nullptr);
}

// Round 7
// 910.934 us; speedup vs baseline: 1.2501x; 1.0972x over previous
//
#include <hip/hip_runtime.h>
#include <hip/hip_bf16.h>

#define NN 50000
#define NE 800000
#define MP 50048           // 391*128 padded rows
#define NBLK 196           // ceil(NN/256)

typedef __attribute__((ext_vector_type(8))) short short8;
typedef __attribute__((ext_vector_type(4))) float f32x4;

__device__ __forceinline__ float b2f(__hip_bfloat16 x) { return __bfloat162float(x); }
__device__ __forceinline__ __hip_bfloat16 f2b(float x) { return __float2bfloat16(x); }
__device__ __forceinline__ float bu2f(unsigned short u) { return __uint_as_float(((unsigned)u) << 16); }
__device__ __forceinline__ unsigned short f2bu(float x) { __hip_bfloat16 b = f2b(x); return *(unsigned short*)&b; }
__device__ __forceinline__ float sigm(float x) { return 1.f / (1.f + __expf(-x)); }
__device__ __forceinline__ float leaky(float x) { return x >= 0.f ? x : 0.2f * x; }

__device__ __forceinline__ void gload16(const void* g, void* l) {
  __builtin_amdgcn_global_load_lds((__attribute__((address_space(1))) void*)(g),
                                   (__attribute__((address_space(3))) void*)(l), 16, 0, 0);
}

__global__ void diag_kernel(float* out, float v) { out[0] = v; }

__global__ void zero_i32(int* p, int n) {
  int i = blockIdx.x * 256 + threadIdx.x;
  if (i < n) p[i] = 0;
}

__global__ void conv_kernel(const float* __restrict__ in, __hip_bfloat16* __restrict__ out, int n) {
  for (int i = blockIdx.x * blockDim.x + threadIdx.x; i < n; i += gridDim.x * blockDim.x)
    out[i] = f2b(in[i]);
}

// vectorized: 4 floats -> 4 bf16 per thread (n % 4 == 0)
__global__ void conv4_kernel(const float* __restrict__ in, __hip_bfloat16* __restrict__ out, int n4) {
  int i = blockIdx.x * 256 + threadIdx.x;
  if (i >= n4) return;
  float4 v = ((const float4*)in)[i];
  ushort4 o;
  o.x = f2bu(v.x); o.y = f2bu(v.y); o.z = f2bu(v.z); o.w = f2bu(v.w);
  ((ushort4*)out)[i] = o;
}

// 4 GRU weight mats (196608 each) -> contiguous bf16 out
__global__ void conv_gruw(const float* __restrict__ p0, const float* __restrict__ p1,
                          const float* __restrict__ p2, const float* __restrict__ p3,
                          __hip_bfloat16* __restrict__ out) {
  int idx = blockIdx.x * 256 + threadIdx.x;  // 786432 total
  int w = idx / 196608, r = idx - w * 196608;
  const float* s = (w == 0) ? p0 : (w == 1) ? p1 : (w == 2) ? p2 : p3;
  out[idx] = f2b(s[r]);
}

// out[r*cols+c] = in[r*ld + coff + c]
__global__ void conv_strided(const float* __restrict__ in, __hip_bfloat16* __restrict__ out,
                             int rows, int cols, int ld, int coff) {
  int idx = blockIdx.x * 256 + threadIdx.x;
  if (idx >= rows * cols) return;
  int r = idx / cols, c = idx - r * cols;
  out[idx] = f2b(in[(size_t)r * ld + coff + c]);
}

// ---------------- unified GEMM: C = A1*B1^T (+ A2*B2^T), K=256 per pass ----------------
// Double-buffered K-loop, counted vmcnt. LDS k-chunk XOR swizzle (both-sides):
// phys chunk c_p holds logical chunk c_p ^ ((row>>1)&3); staged via pre-swizzled
// global source (LDS dest stays linear for global_load_lds), read with same XOR.
#define EPI_BF16 0
#define EPI_SIGM 1
#define EPI_BIAS 2
#define EPI_GRUF 3
#define EPI_GRUS 4
#define EPI_OUT  5
#define EPI_ESED 6

template <int EPI, bool DUAL>
__global__ __launch_bounds__(256) void gemm256(
    const __hip_bfloat16* __restrict__ A1, const __hip_bfloat16* __restrict__ B1,
    const __hip_bfloat16* __restrict__ A2, const __hip_bfloat16* __restrict__ B2,
    void* __restrict__ Cv, int M, int N,
    const float* __restrict__ bi, const float* __restrict__ bh,
    const __hip_bfloat16* __restrict__ RZ, const __hip_bfloat16* __restrict__ T,
    __hip_bfloat16* __restrict__ HP, float* __restrict__ ESp, float* __restrict__ EDp) {
  __shared__ __align__(16) short smem[16384];  // 2 bufs x (As[128][32] + Bs[128][32])
  const int tid = threadIdx.x;
  const int wid = tid >> 6, lane = tid & 63;
  const int m0 = blockIdx.y * 128, n0 = blockIdx.x * 128;
  const int wr = wid >> 1, wc = wid & 1;
  const int sr = lane >> 2;
  const int kp = (((lane & 3) ^ ((lane >> 3) & 3)) * 8);   // staging: pre-swizzled global k-chunk
  const int lrow = lane & 15;
  const int lk = (((lane >> 4) ^ ((lane >> 1) & 3)) * 8);  // read: same XOR ((row>>1)&3 == (lane>>1)&3)
  const int NS = DUAL ? 16 : 8;
  f32x4 acc[4][4];
#pragma unroll
  for (int i = 0; i < 4; ++i)
#pragma unroll
    for (int j = 0; j < 4; ++j) acc[i][j] = (f32x4)0.f;

  auto stage = [&](int s, int buf) {
    const __hip_bfloat16* A = (DUAL && s >= 8) ? A2 : A1;
    const __hip_bfloat16* B = (DUAL && s >= 8) ? B2 : B1;
    const int k0 = (s & 7) * 32;
    short* As = smem + buf * 8192;
    short* Bs = As + 4096;
#pragma unroll
    for (int ss = 0; ss < 2; ++ss) {
      int seg = wid + ss * 4;
      gload16(A + (size_t)(m0 + seg * 16 + sr) * 256 + k0 + kp, &As[seg * 512]);
      gload16(B + (size_t)(n0 + seg * 16 + sr) * 256 + k0 + kp, &Bs[seg * 512]);
    }
  };

  auto compute = [&](int s) {
    const short* As = smem + (s & 1) * 8192;
    const short* Bs = As + 4096;
    short8 af[4], bfv[4];
#pragma unroll
    for (int i = 0; i < 4; ++i) af[i] = *(const short8*)&As[(wr * 64 + i * 16 + lrow) * 32 + lk];
#pragma unroll
    for (int j = 0; j < 4; ++j) bfv[j] = *(const short8*)&Bs[(wc * 64 + j * 16 + lrow) * 32 + lk];
#pragma unroll
    for (int i = 0; i < 4; ++i)
#pragma unroll
      for (int j = 0; j < 4; ++j)
        acc[i][j] = __builtin_amdgcn_mfma_f32_16x16x32_bf16(af[i], bfv[j], acc[i][j], 0, 0, 0);
  };

  stage(0, 0);
  stage(1, 1);
  for (int s = 0; s < NS - 1; ++s) {
    // wait for tile s only: tile s+1's 4 loads may remain in flight (per-wave FIFO retire)
    asm volatile("s_waitcnt vmcnt(4)" ::: "memory");
    __builtin_amdgcn_s_barrier();
    __builtin_amdgcn_sched_barrier(0);
    compute(s);
    // all this wave's LDS reads done before anyone overwrites buf[s&1]
    asm volatile("s_waitcnt lgkmcnt(0)" ::: "memory");
    __builtin_amdgcn_sched_barrier(0);
    __builtin_amdgcn_s_barrier();
    if (s + 2 < NS) stage(s + 2, s & 1);
  }
  asm volatile("s_waitcnt vmcnt(0)" ::: "memory");
  __builtin_amdgcn_s_barrier();
  __builtin_amdgcn_sched_barrier(0);
  compute(NS - 1);

  const int rowb = m0 + wr * 64 + (lane >> 4) * 4;
  const int colb = n0 + wc * 64 + (lane & 15);

  if constexpr (EPI == EPI_ESED) {
    // bi = a_s (flat 256), bh = a_d; head fixed per block (n0 in {0,128})
    const int head = n0 >> 7;
#pragma unroll
    for (int i = 0; i < 4; ++i) {
#pragma unroll
      for (int rr = 0; rr < 4; ++rr) {
        const int row = rowb + i * 16 + rr;
        float ps = 0.f, pd = 0.f;
#pragma unroll
        for (int j = 0; j < 4; ++j) {
          const int col = colb + j * 16;
          float v = acc[i][j][rr];
          if (row < M) ((__hip_bfloat16*)Cv)[(size_t)row * N + col] = f2b(v);
          ps += v * bi[col];
          pd += v * bh[col];
        }
#pragma unroll
        for (int o = 8; o >= 1; o >>= 1) {  // reduce across the 16 lanes sharing this row
          ps += __shfl_xor(ps, o, 64);
          pd += __shfl_xor(pd, o, 64);
        }
        if ((lane & 15) == 0 && row < M) {
          atomicAdd(&ESp[row * 2 + head], ps);
          atomicAdd(&EDp[row * 2 + head], pd);
        }
      }
    }
    return;
  }

#pragma unroll
  for (int i = 0; i < 4; ++i) {
#pragma unroll
    for (int j = 0; j < 4; ++j) {
      const int col = colb + j * 16;
#pragma unroll
      for (int rr = 0; rr < 4; ++rr) {
        const int row = rowb + i * 16 + rr;
        if (row >= M) continue;
        float v = acc[i][j][rr];
        if constexpr (EPI == EPI_BF16) {
          ((__hip_bfloat16*)Cv)[(size_t)row * N + col] = f2b(v);
        } else if constexpr (EPI == EPI_SIGM) {
          ((__hip_bfloat16*)Cv)[(size_t)row * 512 + col] = f2b(sigm(v + bi[col] + bh[col]));
        } else if constexpr (EPI == EPI_BIAS) {
          ((__hip_bfloat16*)Cv)[(size_t)row * 256 + col] = f2b(v + bh[512 + col]);
        } else if constexpr (EPI == EPI_GRUF) {
          float r_ = b2f(RZ[(size_t)row * 512 + col]);
          float z_ = b2f(RZ[(size_t)row * 512 + 256 + col]);
          float n_ = tanhf(v + bi[512 + col] + r_ * bh[512 + col]);
          HP[(size_t)row * 256 + col] = f2b((1.f - z_) * n_);
        } else if constexpr (EPI == EPI_GRUS) {
          float r_ = b2f(RZ[(size_t)row * 512 + col]);
          float z_ = b2f(RZ[(size_t)row * 512 + 256 + col]);
          float t_ = b2f(T[(size_t)row * 256 + col]);          // already + bh_n
          float n_ = tanhf(v + bi[512 + col] + r_ * t_);
          float hp = b2f(HP[(size_t)row * 256 + col]);
          HP[(size_t)row * 256 + col] = f2b(hp + (1.f - z_) * n_ + z_ * hp);
        } else {  // EPI_OUT
          ((float*)Cv)[(size_t)row * 256 + col] = v;
        }
      }
    }
  }
}

// ---------------- CSR build ----------------
__global__ void hist_kernel(const int* __restrict__ dst, int* __restrict__ deg, int ne) {
  for (int e = blockIdx.x * blockDim.x + threadIdx.x; e < ne; e += gridDim.x * blockDim.x)
    atomicAdd(&deg[dst[e]], 1);
}

__global__ void scan1(const int* __restrict__ deg, int* __restrict__ bsum, int n) {
  __shared__ int sd[256];
  int idx = blockIdx.x * 256 + threadIdx.x;
  sd[threadIdx.x] = (idx < n) ? deg[idx] : 0;
  __syncthreads();
  for (int off = 128; off > 0; off >>= 1) {
    if (threadIdx.x < off) sd[threadIdx.x] += sd[threadIdx.x + off];
    __syncthreads();
  }
  if (threadIdx.x == 0) bsum[blockIdx.x] = sd[0];
}

__global__ void scan2(const int* __restrict__ bsum, int* __restrict__ boff, int nb) {
  __shared__ int s[256];
  int t = threadIdx.x;
  int v0 = (t < nb) ? bsum[t] : 0;
  s[t] = v0;
  __syncthreads();
  for (int off = 1; off < 256; off <<= 1) {
    int x = (t >= off) ? s[t - off] : 0;
    __syncthreads();
    s[t] += x;
    __syncthreads();
  }
  if (t < nb) boff[t] = s[t] - v0;
}

__global__ void scan3(const int* __restrict__ deg, const int* __restrict__ boff,
                      int* __restrict__ row_ptr, int* __restrict__ cursor, int n, int ne) {
  __shared__ int s[256];
  int t = threadIdx.x;
  int idx = blockIdx.x * 256 + t;
  int v = (idx < n) ? deg[idx] : 0;
  s[t] = v;
  __syncthreads();
  for (int off = 1; off < 256; off <<= 1) {
    int x = (t >= off) ? s[t - off] : 0;
    __syncthreads();
    s[t] += x;
    __syncthreads();
  }
  if (idx < n) {
    int val = boff[blockIdx.x] + s[t] - v;
    row_ptr[idx] = val;
    cursor[idx] = val;
  }
  if (idx == n) row_ptr[n] = ne;
}

__global__ void scatter_kernel(const int* __restrict__ src, const int* __restrict__ dst,
                               int* __restrict__ cursor, int* __restrict__ srcs, int ne) {
  for (int e = blockIdx.x * blockDim.x + threadIdx.x; e < ne; e += gridDim.x * blockDim.x) {
    int p = atomicAdd(&cursor[dst[e]], 1);
    srcs[p] = src[e];
  }
}

// ---------------- GAT aggregation: one wave per node ----------------
// deg<=64 fast path: per-lane edge logit in registers, shuffle reduce, shfl-broadcast
// phase 2 with 4x-unrolled independent z gathers. All __shfl ops are straight-line
// (full exec); per-lane head select happens AFTER the shfl (divergent shfl = UB).
__device__ __forceinline__ void onl_upd(float& m, float& s, float v) {
  if (v <= m) {
    s += __expf(v - m);
  } else {
    s = s * __expf(m - v) + 1.f;
    m = v;
  }
}

__global__ __launch_bounds__(256) void gat_agg_wave(const int* __restrict__ row_ptr,
                                                    const int* __restrict__ srcs,
                                                    const float* __restrict__ es,
                                                    const float* __restrict__ ed,
                                                    const __hip_bfloat16* __restrict__ z,
                                                    __hip_bfloat16* __restrict__ hout) {
  int node = blockIdx.x * 4 + (threadIdx.x >> 6);
  int lane = threadIdx.x & 63;
  if (node >= NN) return;
  ushort4* outp = (ushort4*)&hout[(size_t)node * 256 + lane * 4];
  int start = row_ptr[node], end = row_ptr[node + 1];
  int deg = end - start;
  if (deg == 0) {
    *outp = make_ushort4(0, 0, 0, 0);
    return;
  }
  float ed0 = ed[node * 2], ed1 = ed[node * 2 + 1];
  int h = lane >> 5;
  float a0 = 0.f, a1 = 0.f, a2 = 0.f, a3 = 0.f;

  if (deg <= 64) {
    int sn = 0;
    float l0 = -1e30f, l1 = -1e30f;
    if (lane < deg) {
      sn = srcs[start + lane];
      float2 ee = *(const float2*)&es[sn * 2];
      l0 = leaky(ee.x + ed0);
      l1 = leaky(ee.y + ed1);
    }
    float m0 = l0, m1 = l1;
#pragma unroll
    for (int off = 32; off > 0; off >>= 1) {
      m0 = fmaxf(m0, __shfl_xor(m0, off, 64));
      m1 = fmaxf(m1, __shfl_xor(m1, off, 64));
    }
    float p0 = (lane < deg) ? __expf(l0 - m0) : 0.f;
    float p1 = (lane < deg) ? __expf(l1 - m1) : 0.f;
    float s0 = p0, s1 = p1;
#pragma unroll
    for (int off = 32; off > 0; off >>= 1) {
      s0 += __shfl_xor(s0, off, 64);
      s1 += __shfl_xor(s1, off, 64);
    }
    float w0 = p0 / s0, w1 = p1 / s1;  // this lane's edge weight, both heads
    const size_t zlo = lane * 4;
    int e = 0;
    for (; e + 4 <= deg; e += 4) {
      int sa = __shfl(sn, e, 64), sb = __shfl(sn, e + 1, 64);
      int sc = __shfl(sn, e + 2, 64), sd = __shfl(sn, e + 3, 64);
      float wa0 = __shfl(w0, e, 64),     wa1 = __shfl(w1, e, 64);
      float wb0 = __shfl(w0, e + 1, 64), wb1 = __shfl(w1, e + 1, 64);
      float wc0 = __shfl(w0, e + 2, 64), wc1 = __shfl(w1, e + 2, 64);
      float wd0 = __shfl(w0, e + 3, 64), wd1 = __shfl(w1, e + 3, 64);
      float wa = h ? wa1 : wa0;
      float wb = h ? wb1 : wb0;
      float wc = h ? wc1 : wc0;
      float wd = h ? wd1 : wd0;
      ushort4 za = *(const ushort4*)&z[(size_t)sa * 256 + zlo];
      ushort4 zb = *(const ushort4*)&z[(size_t)sb * 256 + zlo];
      ushort4 zc = *(const ushort4*)&z[(size_t)sc * 256 + zlo];
      ushort4 zd = *(const ushort4*)&z[(size_t)sd * 256 + zlo];
      a0 = fmaf(wa, bu2f(za.x), a0); a1 = fmaf(wa, bu2f(za.y), a1);
      a2 = fmaf(wa, bu2f(za.z), a2); a3 = fmaf(wa, bu2f(za.w), a3);
      a0 = fmaf(wb, bu2f(zb.x), a0); a1 = fmaf(wb, bu2f(zb.y), a1);
      a2 = fmaf(wb, bu2f(zb.z), a2); a3 = fmaf(wb, bu2f(zb.w), a3);
      a0 = fmaf(wc, bu2f(zc.x), a0); a1 = fmaf(wc, bu2f(zc.y), a1);
      a2 = fmaf(wc, bu2f(zc.z), a2); a3 = fmaf(wc, bu2f(zc.w), a3);
      a0 = fmaf(wd, bu2f(zd.x), a0); a1 = fmaf(wd, bu2f(zd.y), a1);
      a2 = fmaf(wd, bu2f(zd.z), a2); a3 = fmaf(wd, bu2f(zd.w), a3);
    }
    for (; e < deg; ++e) {
      int sa = __shfl(sn, e, 64);
      float wa0 = __shfl(w0, e, 64), wa1 = __shfl(w1, e, 64);
      float wa = h ? wa1 : wa0;
      ushort4 za = *(const ushort4*)&z[(size_t)sa * 256 + zlo];
      a0 = fmaf(wa, bu2f(za.x), a0); a1 = fmaf(wa, bu2f(za.y), a1);
      a2 = fmaf(wa, bu2f(za.z), a2); a3 = fmaf(wa, bu2f(za.w), a3);
    }
  } else {
    // general path (rare): online max/sum then re-read weights
    float m0 = -1e30f, s0 = 0.f, m1 = -1e30f, s1 = 0.f;
    for (int i = start + lane; i < end; i += 64) {
      int sn = srcs[i];
      float e0 = es[sn * 2], e1 = es[sn * 2 + 1];
      onl_upd(m0, s0, leaky(e0 + ed0));
      onl_upd(m1, s1, leaky(e1 + ed1));
    }
#pragma unroll
    for (int off = 32; off > 0; off >>= 1) {
      float om0 = __shfl_xor(m0, off, 64), os0 = __shfl_xor(s0, off, 64);
      float om1 = __shfl_xor(m1, off, 64), os1 = __shfl_xor(s1, off, 64);
      float mm = fmaxf(m0, om0);
      s0 = s0 * __expf(m0 - mm) + os0 * __expf(om0 - mm);
      m0 = mm;
      mm = fmaxf(m1, om1);
      s1 = s1 * __expf(m1 - mm) + os1 * __expf(om1 - mm);
      m1 = mm;
    }
    float rm = h ? m1 : m0;
    float rsi = 1.f / (h ? s1 : s0);
    float edh = h ? ed1 : ed0;
    for (int e = start; e < end; ++e) {
      int sa = srcs[e];
      float2 ee = *(const float2*)&es[sa * 2];
      float w = __expf(leaky((h ? ee.y : ee.x) + edh) - rm) * rsi;
      ushort4 zv = *(const ushort4*)&z[(size_t)sa * 256 + lane * 4];
      a0 = fmaf(w, bu2f(zv.x), a0); a1 = fmaf(w, bu2f(zv.y), a1);
      a2 = fmaf(w, bu2f(zv.z), a2); a3 = fmaf(w, bu2f(zv.w), a3);
    }
  }
  ushort4 o;
  o.x = f2bu(fmaxf(a0, 0.f));
  o.y = f2bu(fmaxf(a1, 0.f));
  o.z = f2bu(fmaxf(a2, 0.f));
  o.w = f2bu(fmaxf(a3, 0.f));
  *outp = o;
}

// ---------------- host ----------------
extern "C" void kernel_launch(void* const* d_in, const int* in_sizes, int n_in,
                              void* d_out, int out_size, void* d_ws, size_t ws_size,
                              hipStream_t stream) {
  const float* in_feat = (const float*)d_in[0];
  const int* srcp = (const int*)d_in[1];
  const int* dstp = (const int*)d_in[2];
  const float* W1 = (const float*)d_in[3];
  const float* as1 = (const float*)d_in[4];
  const float* ad1 = (const float*)d_in[5];
  const float* W2 = (const float*)d_in[6];
  const float* as2 = (const float*)d_in[7];
  const float* ad2 = (const float*)d_in[8];
  const float* wi_f = (const float*)d_in[9];
  const float* wh_f = (const float*)d_in[10];
  const float* bi_f = (const float*)d_in[11];
  const float* bh_f = (const float*)d_in[12];
  const float* wi_b = (const float*)d_in[13];
  const float* wh_b = (const float*)d_in[14];
  const float* bi_b = (const float*)d_in[15];
  const float* bh_b = (const float*)d_in[16];
  // d_in[17] = s_w: dead (softmax over a singleton axis == 1.0)
  const float* lin_w = (const float*)d_in[18];
  (void)in_sizes; (void)n_in; (void)out_size;

  const size_t UNIT = (size_t)MP * 256 * 2;
  char* ws = (char*)d_ws;
  size_t off = 0;
  auto take = [&](size_t bytes) -> void* {
    void* p = ws + off;
    off += (bytes + 255) & ~(size_t)255;
    return p;
  };
  __hip_bfloat16* U0 = (__hip_bfloat16*)take(UNIT);      // x, then T
  __hip_bfloat16* U1 = (__hip_bfloat16*)take(UNIT * 2);  // z (GAT), then RZ (stride 512)
  __hip_bfloat16* h1 = (__hip_bfloat16*)take(UNIT);
  __hip_bfloat16* h2 = (__hip_bfloat16*)take(UNIT);
  __hip_bfloat16* hpF = (__hip_bfloat16*)take(UNIT);     // f0, then f0+f1
  __hip_bfloat16* hpB = (__hip_bfloat16*)take(UNIT);     // b1, then b1+b0
  __hip_bfloat16* wW1 = (__hip_bfloat16*)take(65536 * 2);
  __hip_bfloat16* wW2 = (__hip_bfloat16*)take(65536 * 2);
  __hip_bfloat16* wif = (__hip_bfloat16*)take(196608 * 2);  // order matters: conv_gruw writes
  __hip_bfloat16* whf = (__hip_bfloat16*)take(196608 * 2);  // wif,whf,wib,whb contiguously
  __hip_bfloat16* wib = (__hip_bfloat16*)take(196608 * 2);
  __hip_bfloat16* whb = (__hip_bfloat16*)take(196608 * 2);
  __hip_bfloat16* wlinA = (__hip_bfloat16*)take(65536 * 2);
  __hip_bfloat16* wlinB = (__hip_bfloat16*)take(65536 * 2);
  // deg..ed2 contiguous, zeroed in one launch
  int* deg = (int*)take((size_t)NN * 4);
  float* es1 = (float*)take((size_t)NN * 2 * 4);
  float* ed1 = (float*)take((size_t)NN * 2 * 4);
  float* es2 = (float*)take((size_t)NN * 2 * 4);
  float* ed2 = (float*)take((size_t)NN * 2 * 4);
  int* cursor = (int*)take((size_t)NN * 4);
  int* row_ptr = (int*)take((size_t)(NN + 1) * 4);
  int* bsum = (int*)take(256 * 4);
  int* boff = (int*)take(256 * 4);
  int* srcs = (int*)take((size_t)NE * 4);

  if (off > ws_size) {  // diagnostic: report ws_size via absmax instead of faulting
    diag_kernel<<<1, 1, 0, stream>>>((float*)d_out, (float)ws_size);
    return;
  }

  // conversions
  conv4_kernel<<<12500, 256, 0, stream>>>(in_feat, U0, NN * 64);
  conv_kernel<<<256, 256, 0, stream>>>(W1, wW1, 65536);
  conv_kernel<<<256, 256, 0, stream>>>(W2, wW2, 65536);
  conv_gruw<<<3072, 256, 0, stream>>>(wi_f, wh_f, wi_b, wh_b, wif);
  conv_strided<<<256, 256, 0, stream>>>(lin_w, wlinA, 256, 256, 512, 0);
  conv_strided<<<256, 256, 0, stream>>>(lin_w, wlinB, 256, 256, 512, 256);

  // zero deg + es/ed (contiguous region)
  {
    int zw = (int)(((char*)ed2 - (char*)deg) / 4) + NN * 2;
    zero_i32<<<(zw + 255) / 256, 256, 0, stream>>>(deg, zw);
  }
  hist_kernel<<<1024, 256, 0, stream>>>(dstp, deg, NE);
  scan1<<<NBLK, 256, 0, stream>>>(deg, bsum, NN);
  scan2<<<1, 256, 0, stream>>>(bsum, boff, NBLK);
  scan3<<<NBLK, 256, 0, stream>>>(deg, boff, row_ptr, cursor, NN, NE);
  scatter_kernel<<<1024, 256, 0, stream>>>(srcp, dstp, cursor, srcs, NE);

  dim3 g2(2, MP / 128), g4(4, MP / 128);
  const __hip_bfloat16* wifN = wif + 512 * 256;  // Wi_n slice
  const __hip_bfloat16* whfN = whf + 512 * 256;
  const __hip_bfloat16* wibN = wib + 512 * 256;
  const __hip_bfloat16* whbN = whb + 512 * 256;

  // GAT layer 1: z = x@W1^T (+ fused es/ed); h1 = relu(agg(z))
  gemm256<EPI_ESED, false><<<g2, 256, 0, stream>>>(U0, wW1, nullptr, nullptr, U1, NN, 256,
                                                   as1, ad1, nullptr, nullptr, nullptr, es1, ed1);
  gat_agg_wave<<<12500, 256, 0, stream>>>(row_ptr, srcs, es1, ed1, U1, h1);
  // GAT layer 2
  gemm256<EPI_ESED, false><<<g2, 256, 0, stream>>>(h1, wW2, nullptr, nullptr, U1, NN, 256,
                                                   as2, ad2, nullptr, nullptr, nullptr, es2, ed2);
  gat_agg_wave<<<12500, 256, 0, stream>>>(row_ptr, srcs, es2, ed2, U1, h2);

  // forward GRU: f0 = step(0, h1); fsum = f0 + step(f0, h2)
  gemm256<EPI_SIGM, false><<<g4, 256, 0, stream>>>(h1, wif, nullptr, nullptr, U1, NN, 512,
                                                   bi_f, bh_f, nullptr, nullptr, nullptr, nullptr, nullptr);
  gemm256<EPI_GRUF, false><<<g2, 256, 0, stream>>>(h1, wifN, nullptr, nullptr, nullptr, NN, 256,
                                                   bi_f, bh_f, U1, nullptr, hpF, nullptr, nullptr);
  gemm256<EPI_SIGM, true><<<g4, 256, 0, stream>>>(h2, wif, hpF, whf, U1, NN, 512,
                                                  bi_f, bh_f, nullptr, nullptr, nullptr, nullptr, nullptr);
  gemm256<EPI_BIAS, false><<<g2, 256, 0, stream>>>(hpF, whfN, nullptr, nullptr, U0, NN, 256,
                                                   nullptr, bh_f, nullptr, nullptr, nullptr, nullptr, nullptr);
  gemm256<EPI_GRUS, false><<<g2, 256, 0, stream>>>(h2, wifN, nullptr, nullptr, nullptr, NN, 256,
                                                   bi_f, nullptr, U1, U0, hpF, nullptr, nullptr);

  // backward GRU: b1 = step(0, h2); bsum = b1 + step(b1, h1)
  gemm256<EPI_SIGM, false><<<g4, 256, 0, stream>>>(h2, wib, nullptr, nullptr, U1, NN, 512,
                                                   bi_b, bh_b, nullptr, nullptr, nullptr, nullptr, nullptr);
  gemm256<EPI_GRUF, false><<<g2, 256, 0, stream>>>(h2, wibN, nullptr, nullptr, nullptr, NN, 256,
                                                   bi_b, bh_b, U1, nullptr, hpB, nullptr, nullptr);
  gemm256<EPI_SIGM, true><<<g4, 256, 0, stream>>>(h1, wib, hpB, whb, U1, NN, 512,
                                                  bi_b, bh_b, nullptr, nullptr, nullptr, nullptr, nullptr);
  gemm256<EPI_BIAS, false><<<g2, 256, 0, stream>>>(hpB, whbN, nullptr, nullptr, U0, NN, 256,
                                                   nullptr, bh_b, nullptr, nullptr, nullptr, nullptr, nullptr);
  gemm256<EPI_GRUS, false><<<g2, 256, 0, stream>>>(h1, wibN, nullptr, nullptr, nullptr, NN, 256,
                                                   bi_b, nullptr, U1, U0, hpB, nullptr, nullptr);

  // out = fsum@linA^T + bsum@linB^T
  gemm256<EPI_OUT, true><<<g2, 256, 0, stream>>>(hpF, wlinA, hpB, wlinB, d_out, NN, 256,
                                                 nullptr, nullptr, nullptr, nullptr, nullptr, nullptr, nullptr);
}

// Round 8
// 874.989 us; speedup vs baseline: 1.3014x; 1.0411x over previous
//
#include <hip/hip_runtime.h>
#include <hip/hip_bf16.h>

#define NN 50000
#define NE 800000
#define MP 50048           // 391*128 padded rows
#define NBLK 196           // ceil(NN/256)

typedef __attribute__((ext_vector_type(8))) short short8;
typedef __attribute__((ext_vector_type(4))) float f32x4;

__device__ __forceinline__ float b2f(__hip_bfloat16 x) { return __bfloat162float(x); }
__device__ __forceinline__ __hip_bfloat16 f2b(float x) { return __float2bfloat16(x); }
__device__ __forceinline__ float bu2f(unsigned short u) { return __uint_as_float(((unsigned)u) << 16); }
__device__ __forceinline__ unsigned short f2bu(float x) { __hip_bfloat16 b = f2b(x); return *(unsigned short*)&b; }
__device__ __forceinline__ float sigm(float x) { return 1.f / (1.f + __expf(-x)); }
__device__ __forceinline__ float leaky(float x) { return x >= 0.f ? x : 0.2f * x; }

__device__ __forceinline__ void gload16(const void* g, void* l) {
  __builtin_amdgcn_global_load_lds((__attribute__((address_space(1))) void*)(g),
                                   (__attribute__((address_space(3))) void*)(l), 16, 0, 0);
}

__global__ void diag_kernel(float* out, float v) { out[0] = v; }

__global__ void zero_i32(int* p, int n) {
  int i = blockIdx.x * 256 + threadIdx.x;
  if (i < n) p[i] = 0;
}

__global__ void conv_kernel(const float* __restrict__ in, __hip_bfloat16* __restrict__ out, int n) {
  for (int i = blockIdx.x * blockDim.x + threadIdx.x; i < n; i += gridDim.x * blockDim.x)
    out[i] = f2b(in[i]);
}

// vectorized: 4 floats -> 4 bf16 per thread (n % 4 == 0)
__global__ void conv4_kernel(const float* __restrict__ in, __hip_bfloat16* __restrict__ out, int n4) {
  int i = blockIdx.x * 256 + threadIdx.x;
  if (i >= n4) return;
  float4 v = ((const float4*)in)[i];
  ushort4 o;
  o.x = f2bu(v.x); o.y = f2bu(v.y); o.z = f2bu(v.z); o.w = f2bu(v.w);
  ((ushort4*)out)[i] = o;
}

// 4 GRU weight mats (196608 each) -> contiguous bf16 out
__global__ void conv_gruw(const float* __restrict__ p0, const float* __restrict__ p1,
                          const float* __restrict__ p2, const float* __restrict__ p3,
                          __hip_bfloat16* __restrict__ out) {
  int idx = blockIdx.x * 256 + threadIdx.x;  // 786432 total
  int w = idx / 196608, r = idx - w * 196608;
  const float* s = (w == 0) ? p0 : (w == 1) ? p1 : (w == 2) ? p2 : p3;
  out[idx] = f2b(s[r]);
}

// out[r*cols+c] = in[r*ld + coff + c]
__global__ void conv_strided(const float* __restrict__ in, __hip_bfloat16* __restrict__ out,
                             int rows, int cols, int ld, int coff) {
  int idx = blockIdx.x * 256 + threadIdx.x;
  if (idx >= rows * cols) return;
  int r = idx / cols, c = idx - r * cols;
  out[idx] = f2b(in[(size_t)r * ld + coff + c]);
}

// ---------------- unified GEMM: C = A1*B1^T (+ A2*B2^T), K=256 per pass ----------------
// Double-buffered K-loop, counted vmcnt, LDS k-chunk XOR swizzle (both-sides).
// XCD-chunked bijective block swizzle (T1/m204): consecutive work IDs (the column
// blocks sharing one A row-panel) land on the SAME XCD -> A-tile L2 reuse.
#define EPI_BF16 0
#define EPI_SIGM 1
#define EPI_BIAS 2
#define EPI_GRUF 3
#define EPI_GRUS 4
#define EPI_OUT  5
#define EPI_ESED 6

template <int EPI, bool DUAL>
__global__ __launch_bounds__(256) void gemm256(
    const __hip_bfloat16* __restrict__ A1, const __hip_bfloat16* __restrict__ B1,
    const __hip_bfloat16* __restrict__ A2, const __hip_bfloat16* __restrict__ B2,
    void* __restrict__ Cv, int M, int N,
    const float* __restrict__ bi, const float* __restrict__ bh,
    const __hip_bfloat16* __restrict__ RZ, const __hip_bfloat16* __restrict__ T,
    __hip_bfloat16* __restrict__ HP, float* __restrict__ ESp, float* __restrict__ EDp) {
  __shared__ __align__(16) short smem[16384];  // 2 bufs x (As[128][32] + Bs[128][32])
  const int tid = threadIdx.x;
  const int wid = tid >> 6, lane = tid & 63;

  // XCD-chunked bijective swizzle (m204): XCD k gets a contiguous chunk of work IDs.
  const int NW = gridDim.x * gridDim.y;
  const int wg = blockIdx.x + gridDim.x * blockIdx.y;
  const int q = NW >> 3, r8 = NW & 7;
  const int xcd = wg & 7, j = wg >> 3;
  const int wid2 = (xcd < r8 ? xcd * (q + 1) : r8 * (q + 1) + (xcd - r8) * q) + j;
  const int m0 = (wid2 / gridDim.x) * 128, n0 = (wid2 % gridDim.x) * 128;

  const int wr = wid >> 1, wc = wid & 1;
  const int sr = lane >> 2;
  const int kp = (((lane & 3) ^ ((lane >> 3) & 3)) * 8);   // staging: pre-swizzled global k-chunk
  const int lrow = lane & 15;
  const int lk = (((lane >> 4) ^ ((lane >> 1) & 3)) * 8);  // read: same XOR
  const int NS = DUAL ? 16 : 8;
  f32x4 acc[4][4];
#pragma unroll
  for (int i = 0; i < 4; ++i)
#pragma unroll
    for (int j2 = 0; j2 < 4; ++j2) acc[i][j2] = (f32x4)0.f;

  auto stage = [&](int s, int buf) {
    const __hip_bfloat16* A = (DUAL && s >= 8) ? A2 : A1;
    const __hip_bfloat16* B = (DUAL && s >= 8) ? B2 : B1;
    const int k0 = (s & 7) * 32;
    short* As = smem + buf * 8192;
    short* Bs = As + 4096;
#pragma unroll
    for (int ss = 0; ss < 2; ++ss) {
      int seg = wid + ss * 4;
      gload16(A + (size_t)(m0 + seg * 16 + sr) * 256 + k0 + kp, &As[seg * 512]);
      gload16(B + (size_t)(n0 + seg * 16 + sr) * 256 + k0 + kp, &Bs[seg * 512]);
    }
  };

  auto compute = [&](int s) {
    const short* As = smem + (s & 1) * 8192;
    const short* Bs = As + 4096;
    short8 af[4], bfv[4];
#pragma unroll
    for (int i = 0; i < 4; ++i) af[i] = *(const short8*)&As[(wr * 64 + i * 16 + lrow) * 32 + lk];
#pragma unroll
    for (int j2 = 0; j2 < 4; ++j2) bfv[j2] = *(const short8*)&Bs[(wc * 64 + j2 * 16 + lrow) * 32 + lk];
#pragma unroll
    for (int i = 0; i < 4; ++i)
#pragma unroll
      for (int j2 = 0; j2 < 4; ++j2)
        acc[i][j2] = __builtin_amdgcn_mfma_f32_16x16x32_bf16(af[i], bfv[j2], acc[i][j2], 0, 0, 0);
  };

  stage(0, 0);
  stage(1, 1);
  for (int s = 0; s < NS - 1; ++s) {
    asm volatile("s_waitcnt vmcnt(4)" ::: "memory");
    __builtin_amdgcn_s_barrier();
    __builtin_amdgcn_sched_barrier(0);
    compute(s);
    asm volatile("s_waitcnt lgkmcnt(0)" ::: "memory");
    __builtin_amdgcn_sched_barrier(0);
    __builtin_amdgcn_s_barrier();
    if (s + 2 < NS) stage(s + 2, s & 1);
  }
  asm volatile("s_waitcnt vmcnt(0)" ::: "memory");
  __builtin_amdgcn_s_barrier();
  __builtin_amdgcn_sched_barrier(0);
  compute(NS - 1);

  const int rowb = m0 + wr * 64 + (lane >> 4) * 4;
  const int colb = n0 + wc * 64 + (lane & 15);

  if constexpr (EPI == EPI_ESED) {
    // bi = a_s (flat 256), bh = a_d; head fixed per block (n0 in {0,128})
    const int head = n0 >> 7;
#pragma unroll
    for (int i = 0; i < 4; ++i) {
#pragma unroll
      for (int rr = 0; rr < 4; ++rr) {
        const int row = rowb + i * 16 + rr;
        float ps = 0.f, pd = 0.f;
#pragma unroll
        for (int j2 = 0; j2 < 4; ++j2) {
          const int col = colb + j2 * 16;
          float v = acc[i][j2][rr];
          if (row < M) ((__hip_bfloat16*)Cv)[(size_t)row * N + col] = f2b(v);
          ps += v * bi[col];
          pd += v * bh[col];
        }
#pragma unroll
        for (int o = 8; o >= 1; o >>= 1) {
          ps += __shfl_xor(ps, o, 64);
          pd += __shfl_xor(pd, o, 64);
        }
        if ((lane & 15) == 0 && row < M) {
          atomicAdd(&ESp[row * 2 + head], ps);
          atomicAdd(&EDp[row * 2 + head], pd);
        }
      }
    }
    return;
  }

#pragma unroll
  for (int i = 0; i < 4; ++i) {
#pragma unroll
    for (int j2 = 0; j2 < 4; ++j2) {
      const int col = colb + j2 * 16;
#pragma unroll
      for (int rr = 0; rr < 4; ++rr) {
        const int row = rowb + i * 16 + rr;
        if (row >= M) continue;
        float v = acc[i][j2][rr];
        if constexpr (EPI == EPI_BF16) {
          ((__hip_bfloat16*)Cv)[(size_t)row * N + col] = f2b(v);
        } else if constexpr (EPI == EPI_SIGM) {
          ((__hip_bfloat16*)Cv)[(size_t)row * 512 + col] = f2b(sigm(v + bi[col] + bh[col]));
        } else if constexpr (EPI == EPI_BIAS) {
          ((__hip_bfloat16*)Cv)[(size_t)row * 256 + col] = f2b(v + bh[512 + col]);
        } else if constexpr (EPI == EPI_GRUF) {
          float r_ = b2f(RZ[(size_t)row * 512 + col]);
          float z_ = b2f(RZ[(size_t)row * 512 + 256 + col]);
          float n_ = tanhf(v + bi[512 + col] + r_ * bh[512 + col]);
          HP[(size_t)row * 256 + col] = f2b((1.f - z_) * n_);
        } else if constexpr (EPI == EPI_GRUS) {
          float r_ = b2f(RZ[(size_t)row * 512 + col]);
          float z_ = b2f(RZ[(size_t)row * 512 + 256 + col]);
          float t_ = b2f(T[(size_t)row * 256 + col]);          // already + bh_n
          float n_ = tanhf(v + bi[512 + col] + r_ * t_);
          float hp = b2f(HP[(size_t)row * 256 + col]);
          HP[(size_t)row * 256 + col] = f2b(hp + (1.f - z_) * n_ + z_ * hp);
        } else {  // EPI_OUT
          ((float*)Cv)[(size_t)row * 256 + col] = v;
        }
      }
    }
  }
}

// ---------------- CSR build ----------------
__global__ void hist_kernel(const int* __restrict__ dst, int* __restrict__ deg, int ne) {
  for (int e = blockIdx.x * blockDim.x + threadIdx.x; e < ne; e += gridDim.x * blockDim.x)
    atomicAdd(&deg[dst[e]], 1);
}

__global__ void scan1(const int* __restrict__ deg, int* __restrict__ bsum, int n) {
  __shared__ int sd[256];
  int idx = blockIdx.x * 256 + threadIdx.x;
  sd[threadIdx.x] = (idx < n) ? deg[idx] : 0;
  __syncthreads();
  for (int off = 128; off > 0; off >>= 1) {
    if (threadIdx.x < off) sd[threadIdx.x] += sd[threadIdx.x + off];
    __syncthreads();
  }
  if (threadIdx.x == 0) bsum[blockIdx.x] = sd[0];
}

__global__ void scan2(const int* __restrict__ bsum, int* __restrict__ boff, int nb) {
  __shared__ int s[256];
  int t = threadIdx.x;
  int v0 = (t < nb) ? bsum[t] : 0;
  s[t] = v0;
  __syncthreads();
  for (int off = 1; off < 256; off <<= 1) {
    int x = (t >= off) ? s[t - off] : 0;
    __syncthreads();
    s[t] += x;
    __syncthreads();
  }
  if (t < nb) boff[t] = s[t] - v0;
}

__global__ void scan3(const int* __restrict__ deg, const int* __restrict__ boff,
                      int* __restrict__ row_ptr, int* __restrict__ cursor, int n, int ne) {
  __shared__ int s[256];
  int t = threadIdx.x;
  int idx = blockIdx.x * 256 + t;
  int v = (idx < n) ? deg[idx] : 0;
  s[t] = v;
  __syncthreads();
  for (int off = 1; off < 256; off <<= 1) {
    int x = (t >= off) ? s[t - off] : 0;
    __syncthreads();
    s[t] += x;
    __syncthreads();
  }
  if (idx < n) {
    int val = boff[blockIdx.x] + s[t] - v;
    row_ptr[idx] = val;
    cursor[idx] = val;
  }
  if (idx == n) row_ptr[n] = ne;
}

__global__ void scatter_kernel(const int* __restrict__ src, const int* __restrict__ dst,
                               int* __restrict__ cursor, int* __restrict__ srcs, int ne) {
  for (int e = blockIdx.x * blockDim.x + threadIdx.x; e < ne; e += gridDim.x * blockDim.x) {
    int p = atomicAdd(&cursor[dst[e]], 1);
    srcs[p] = src[e];
  }
}

// ---------------- GAT aggregation: one wave per node ----------------
__device__ __forceinline__ void onl_upd(float& m, float& s, float v) {
  if (v <= m) {
    s += __expf(v - m);
  } else {
    s = s * __expf(m - v) + 1.f;
    m = v;
  }
}

__global__ __launch_bounds__(256) void gat_agg_wave(const int* __restrict__ row_ptr,
                                                    const int* __restrict__ srcs,
                                                    const float* __restrict__ es,
                                                    const float* __restrict__ ed,
                                                    const __hip_bfloat16* __restrict__ z,
                                                    __hip_bfloat16* __restrict__ hout) {
  int node = blockIdx.x * 4 + (threadIdx.x >> 6);
  int lane = threadIdx.x & 63;
  if (node >= NN) return;
  ushort4* outp = (ushort4*)&hout[(size_t)node * 256 + lane * 4];
  int start = row_ptr[node], end = row_ptr[node + 1];
  int deg = end - start;
  if (deg == 0) {
    *outp = make_ushort4(0, 0, 0, 0);
    return;
  }
  float ed0 = ed[node * 2], ed1 = ed[node * 2 + 1];
  int h = lane >> 5;
  float a0 = 0.f, a1 = 0.f, a2 = 0.f, a3 = 0.f;

  if (deg <= 64) {
    int sn = 0;
    float l0 = -1e30f, l1 = -1e30f;
    if (lane < deg) {
      sn = srcs[start + lane];
      float2 ee = *(const float2*)&es[sn * 2];
      l0 = leaky(ee.x + ed0);
      l1 = leaky(ee.y + ed1);
    }
    float m0 = l0, m1 = l1;
#pragma unroll
    for (int off = 32; off > 0; off >>= 1) {
      m0 = fmaxf(m0, __shfl_xor(m0, off, 64));
      m1 = fmaxf(m1, __shfl_xor(m1, off, 64));
    }
    float p0 = (lane < deg) ? __expf(l0 - m0) : 0.f;
    float p1 = (lane < deg) ? __expf(l1 - m1) : 0.f;
    float s0 = p0, s1 = p1;
#pragma unroll
    for (int off = 32; off > 0; off >>= 1) {
      s0 += __shfl_xor(s0, off, 64);
      s1 += __shfl_xor(s1, off, 64);
    }
    float w0 = p0 / s0, w1 = p1 / s1;  // this lane's edge weight, both heads
    const size_t zlo = lane * 4;
    int e = 0;
    for (; e + 4 <= deg; e += 4) {
      int sa = __shfl(sn, e, 64), sb = __shfl(sn, e + 1, 64);
      int sc = __shfl(sn, e + 2, 64), sd = __shfl(sn, e + 3, 64);
      float wa0 = __shfl(w0, e, 64),     wa1 = __shfl(w1, e, 64);
      float wb0 = __shfl(w0, e + 1, 64), wb1 = __shfl(w1, e + 1, 64);
      float wc0 = __shfl(w0, e + 2, 64), wc1 = __shfl(w1, e + 2, 64);
      float wd0 = __shfl(w0, e + 3, 64), wd1 = __shfl(w1, e + 3, 64);
      float wa = h ? wa1 : wa0;
      float wb = h ? wb1 : wb0;
      float wc = h ? wc1 : wc0;
      float wd = h ? wd1 : wd0;
      ushort4 za = *(const ushort4*)&z[(size_t)sa * 256 + zlo];
      ushort4 zb = *(const ushort4*)&z[(size_t)sb * 256 + zlo];
      ushort4 zc = *(const ushort4*)&z[(size_t)sc * 256 + zlo];
      ushort4 zd = *(const ushort4*)&z[(size_t)sd * 256 + zlo];
      a0 = fmaf(wa, bu2f(za.x), a0); a1 = fmaf(wa, bu2f(za.y), a1);
      a2 = fmaf(wa, bu2f(za.z), a2); a3 = fmaf(wa, bu2f(za.w), a3);
      a0 = fmaf(wb, bu2f(zb.x), a0); a1 = fmaf(wb, bu2f(zb.y), a1);
      a2 = fmaf(wb, bu2f(zb.z), a2); a3 = fmaf(wb, bu2f(zb.w), a3);
      a0 = fmaf(wc, bu2f(zc.x), a0); a1 = fmaf(wc, bu2f(zc.y), a1);
      a2 = fmaf(wc, bu2f(zc.z), a2); a3 = fmaf(wc, bu2f(zc.w), a3);
      a0 = fmaf(wd, bu2f(zd.x), a0); a1 = fmaf(wd, bu2f(zd.y), a1);
      a2 = fmaf(wd, bu2f(zd.z), a2); a3 = fmaf(wd, bu2f(zd.w), a3);
    }
    for (; e < deg; ++e) {
      int sa = __shfl(sn, e, 64);
      float wa0 = __shfl(w0, e, 64), wa1 = __shfl(w1, e, 64);
      float wa = h ? wa1 : wa0;
      ushort4 za = *(const ushort4*)&z[(size_t)sa * 256 + zlo];
      a0 = fmaf(wa, bu2f(za.x), a0); a1 = fmaf(wa, bu2f(za.y), a1);
      a2 = fmaf(wa, bu2f(za.z), a2); a3 = fmaf(wa, bu2f(za.w), a3);
    }
  } else {
    float m0 = -1e30f, s0 = 0.f, m1 = -1e30f, s1 = 0.f;
    for (int i = start + lane; i < end; i += 64) {
      int sn = srcs[i];
      float e0 = es[sn * 2], e1 = es[sn * 2 + 1];
      onl_upd(m0, s0, leaky(e0 + ed0));
      onl_upd(m1, s1, leaky(e1 + ed1));
    }
#pragma unroll
    for (int off = 32; off > 0; off >>= 1) {
      float om0 = __shfl_xor(m0, off, 64), os0 = __shfl_xor(s0, off, 64);
      float om1 = __shfl_xor(m1, off, 64), os1 = __shfl_xor(s1, off, 64);
      float mm = fmaxf(m0, om0);
      s0 = s0 * __expf(m0 - mm) + os0 * __expf(om0 - mm);
      m0 = mm;
      mm = fmaxf(m1, om1);
      s1 = s1 * __expf(m1 - mm) + os1 * __expf(om1 - mm);
      m1 = mm;
    }
    float rm = h ? m1 : m0;
    float rsi = 1.f / (h ? s1 : s0);
    float edh = h ? ed1 : ed0;
    for (int e = start; e < end; ++e) {
      int sa = srcs[e];
      float2 ee = *(const float2*)&es[sa * 2];
      float w = __expf(leaky((h ? ee.y : ee.x) + edh) - rm) * rsi;
      ushort4 zv = *(const ushort4*)&z[(size_t)sa * 256 + lane * 4];
      a0 = fmaf(w, bu2f(zv.x), a0); a1 = fmaf(w, bu2f(zv.y), a1);
      a2 = fmaf(w, bu2f(zv.z), a2); a3 = fmaf(w, bu2f(zv.w), a3);
    }
  }
  ushort4 o;
  o.x = f2bu(fmaxf(a0, 0.f));
  o.y = f2bu(fmaxf(a1, 0.f));
  o.z = f2bu(fmaxf(a2, 0.f));
  o.w = f2bu(fmaxf(a3, 0.f));
  *outp = o;
}

// ---------------- host ----------------
extern "C" void kernel_launch(void* const* d_in, const int* in_sizes, int n_in,
                              void* d_out, int out_size, void* d_ws, size_t ws_size,
                              hipStream_t stream) {
  const float* in_feat = (const float*)d_in[0];
  const int* srcp = (const int*)d_in[1];
  const int* dstp = (const int*)d_in[2];
  const float* W1 = (const float*)d_in[3];
  const float* as1 = (const float*)d_in[4];
  const float* ad1 = (const float*)d_in[5];
  const float* W2 = (const float*)d_in[6];
  const float* as2 = (const float*)d_in[7];
  const float* ad2 = (const float*)d_in[8];
  const float* wi_f = (const float*)d_in[9];
  const float* wh_f = (const float*)d_in[10];
  const float* bi_f = (const float*)d_in[11];
  const float* bh_f = (const float*)d_in[12];
  const float* wi_b = (const float*)d_in[13];
  const float* wh_b = (const float*)d_in[14];
  const float* bi_b = (const float*)d_in[15];
  const float* bh_b = (const float*)d_in[16];
  // d_in[17] = s_w: dead (softmax over a singleton axis == 1.0)
  const float* lin_w = (const float*)d_in[18];
  (void)in_sizes; (void)n_in; (void)out_size;

  const size_t UNIT = (size_t)MP * 256 * 2;
  char* ws = (char*)d_ws;
  size_t off = 0;
  auto take = [&](size_t bytes) -> void* {
    void* p = ws + off;
    off += (bytes + 255) & ~(size_t)255;
    return p;
  };
  __hip_bfloat16* U0 = (__hip_bfloat16*)take(UNIT);      // x, then T
  __hip_bfloat16* U1 = (__hip_bfloat16*)take(UNIT * 2);  // z (GAT), then RZ (stride 512)
  __hip_bfloat16* h1 = (__hip_bfloat16*)take(UNIT);
  __hip_bfloat16* h2 = (__hip_bfloat16*)take(UNIT);
  __hip_bfloat16* hpF = (__hip_bfloat16*)take(UNIT);     // f0, then f0+f1
  __hip_bfloat16* hpB = (__hip_bfloat16*)take(UNIT);     // b1, then b1+b0
  __hip_bfloat16* wW1 = (__hip_bfloat16*)take(65536 * 2);
  __hip_bfloat16* wW2 = (__hip_bfloat16*)take(65536 * 2);
  __hip_bfloat16* wif = (__hip_bfloat16*)take(196608 * 2);  // order matters: conv_gruw writes
  __hip_bfloat16* whf = (__hip_bfloat16*)take(196608 * 2);  // wif,whf,wib,whb contiguously
  __hip_bfloat16* wib = (__hip_bfloat16*)take(196608 * 2);
  __hip_bfloat16* whb = (__hip_bfloat16*)take(196608 * 2);
  __hip_bfloat16* wlinA = (__hip_bfloat16*)take(65536 * 2);
  __hip_bfloat16* wlinB = (__hip_bfloat16*)take(65536 * 2);
  // deg..ed2 contiguous, zeroed in one launch
  int* deg = (int*)take((size_t)NN * 4);
  float* es1 = (float*)take((size_t)NN * 2 * 4);
  float* ed1 = (float*)take((size_t)NN * 2 * 4);
  float* es2 = (float*)take((size_t)NN * 2 * 4);
  float* ed2 = (float*)take((size_t)NN * 2 * 4);
  int* cursor = (int*)take((size_t)NN * 4);
  int* row_ptr = (int*)take((size_t)(NN + 1) * 4);
  int* bsum = (int*)take(256 * 4);
  int* boff = (int*)take(256 * 4);
  int* srcs = (int*)take((size_t)NE * 4);

  if (off > ws_size) {  // diagnostic: report ws_size via absmax instead of faulting
    diag_kernel<<<1, 1, 0, stream>>>((float*)d_out, (float)ws_size);
    return;
  }

  // conversions
  conv4_kernel<<<12500, 256, 0, stream>>>(in_feat, U0, NN * 64);
  conv_kernel<<<256, 256, 0, stream>>>(W1, wW1, 65536);
  conv_kernel<<<256, 256, 0, stream>>>(W2, wW2, 65536);
  conv_gruw<<<3072, 256, 0, stream>>>(wi_f, wh_f, wi_b, wh_b, wif);
  conv_strided<<<256, 256, 0, stream>>>(lin_w, wlinA, 256, 256, 512, 0);
  conv_strided<<<256, 256, 0, stream>>>(lin_w, wlinB, 256, 256, 512, 256);

  // zero deg + es/ed (contiguous region)
  {
    int zw = (int)(((char*)ed2 - (char*)deg) / 4) + NN * 2;
    zero_i32<<<(zw + 255) / 256, 256, 0, stream>>>(deg, zw);
  }
  hist_kernel<<<1024, 256, 0, stream>>>(dstp, deg, NE);
  scan1<<<NBLK, 256, 0, stream>>>(deg, bsum, NN);
  scan2<<<1, 256, 0, stream>>>(bsum, boff, NBLK);
  scan3<<<NBLK, 256, 0, stream>>>(deg, boff, row_ptr, cursor, NN, NE);
  scatter_kernel<<<1024, 256, 0, stream>>>(srcp, dstp, cursor, srcs, NE);

  dim3 g2(2, MP / 128), g4(4, MP / 128);
  const __hip_bfloat16* wifN = wif + 512 * 256;  // Wi_n slice
  const __hip_bfloat16* whfN = whf + 512 * 256;
  const __hip_bfloat16* wibN = wib + 512 * 256;
  const __hip_bfloat16* whbN = whb + 512 * 256;

  // GAT layer 1: z = x@W1^T (+ fused es/ed); h1 = relu(agg(z))
  gemm256<EPI_ESED, false><<<g2, 256, 0, stream>>>(U0, wW1, nullptr, nullptr, U1, NN, 256,
                                                   as1, ad1, nullptr, nullptr, nullptr, es1, ed1);
  gat_agg_wave<<<12500, 256, 0, stream>>>(row_ptr, srcs, es1, ed1, U1, h1);
  // GAT layer 2
  gemm256<EPI_ESED, false><<<g2, 256, 0, stream>>>(h1, wW2, nullptr, nullptr, U1, NN, 256,
                                                   as2, ad2, nullptr, nullptr, nullptr, es2, ed2);
  gat_agg_wave<<<12500, 256, 0, stream>>>(row_ptr, srcs, es2, ed2, U1, h2);

  // forward GRU: f0 = step(0, h1); fsum = f0 + step(f0, h2)
  gemm256<EPI_SIGM, false><<<g4, 256, 0, stream>>>(h1, wif, nullptr, nullptr, U1, NN, 512,
                                                   bi_f, bh_f, nullptr, nullptr, nullptr, nullptr, nullptr);
  gemm256<EPI_GRUF, false><<<g2, 256, 0, stream>>>(h1, wifN, nullptr, nullptr, nullptr, NN, 256,
                                                   bi_f, bh_f, U1, nullptr, hpF, nullptr, nullptr);
  gemm256<EPI_SIGM, true><<<g4, 256, 0, stream>>>(h2, wif, hpF, whf, U1, NN, 512,
                                                  bi_f, bh_f, nullptr, nullptr, nullptr, nullptr, nullptr);
  gemm256<EPI_BIAS, false><<<g2, 256, 0, stream>>>(hpF, whfN, nullptr, nullptr, U0, NN, 256,
                                                   nullptr, bh_f, nullptr, nullptr, nullptr, nullptr, nullptr);
  gemm256<EPI_GRUS, false><<<g2, 256, 0, stream>>>(h2, wifN, nullptr, nullptr, nullptr, NN, 256,
                                                   bi_f, nullptr, U1, U0, hpF, nullptr, nullptr);

  // backward GRU: b1 = step(0, h2); bsum = b1 + step(b1, h1)
  gemm256<EPI_SIGM, false><<<g4, 256, 0, stream>>>(h2, wib, nullptr, nullptr, U1, NN, 512,
                                                   bi_b, bh_b, nullptr, nullptr, nullptr, nullptr, nullptr);
  gemm256<EPI_GRUF, false><<<g2, 256, 0, stream>>>(h2, wibN, nullptr, nullptr, nullptr, NN, 256,
                                                   bi_b, bh_b, U1, nullptr, hpB, nullptr, nullptr);
  gemm256<EPI_SIGM, true><<<g4, 256, 0, stream>>>(h1, wib, hpB, whb, U1, NN, 512,
                                                  bi_b, bh_b, nullptr, nullptr, nullptr, nullptr, nullptr);
  gemm256<EPI_BIAS, false><<<g2, 256, 0, stream>>>(hpB, whbN, nullptr, nullptr, U0, NN, 256,
                                                   nullptr, bh_b, nullptr, nullptr, nullptr, nullptr, nullptr);
  gemm256<EPI_GRUS, false><<<g2, 256, 0, stream>>>(h1, wibN, nullptr, nullptr, nullptr, NN, 256,
                                                   bi_b, nullptr, U1, U0, hpB, nullptr, nullptr);

  // out = fsum@linA^T + bsum@linB^T
  gemm256<EPI_OUT, true><<<g2, 256, 0, stream>>>(hpF, wlinA, hpB, wlinB, d_out, NN, 256,
                                                 nullptr, nullptr, nullptr, nullptr, nullptr, nullptr, nullptr);
}

// Round 9
// 685.391 us; speedup vs baseline: 1.6614x; 1.2766x over previous
//
#include <hip/hip_runtime.h>
#include <hip/hip_bf16.h>

#define NN 50000
#define NE 800000
#define MP 50048           // 391*128 padded rows
#define NBLK 196           // ceil(NN/256)

typedef __attribute__((ext_vector_type(8))) short short8;
typedef __attribute__((ext_vector_type(4))) float f32x4;

__device__ __forceinline__ float b2f(__hip_bfloat16 x) { return __bfloat162float(x); }
__device__ __forceinline__ __hip_bfloat16 f2b(float x) { return __float2bfloat16(x); }
__device__ __forceinline__ float bu2f(unsigned short u) { return __uint_as_float(((unsigned)u) << 16); }
__device__ __forceinline__ unsigned short f2bu(float x) { __hip_bfloat16 b = f2b(x); return *(unsigned short*)&b; }
__device__ __forceinline__ float sigm(float x) { return 1.f / (1.f + __expf(-x)); }
__device__ __forceinline__ float leaky(float x) { return x >= 0.f ? x : 0.2f * x; }

__device__ __forceinline__ void gload16(const void* g, void* l) {
  __builtin_amdgcn_global_load_lds((__attribute__((address_space(1))) void*)(g),
                                   (__attribute__((address_space(3))) void*)(l), 16, 0, 0);
}

__global__ void diag_kernel(float* out, float v) { out[0] = v; }

__global__ void zero_i32(int* p, int n) {
  int i = blockIdx.x * 256 + threadIdx.x;
  if (i < n) p[i] = 0;
}

__global__ void conv_kernel(const float* __restrict__ in, __hip_bfloat16* __restrict__ out, int n) {
  for (int i = blockIdx.x * blockDim.x + threadIdx.x; i < n; i += gridDim.x * blockDim.x)
    out[i] = f2b(in[i]);
}

__global__ void conv4_kernel(const float* __restrict__ in, __hip_bfloat16* __restrict__ out, int n4) {
  int i = blockIdx.x * 256 + threadIdx.x;
  if (i >= n4) return;
  float4 v = ((const float4*)in)[i];
  ushort4 o;
  o.x = f2bu(v.x); o.y = f2bu(v.y); o.z = f2bu(v.z); o.w = f2bu(v.w);
  ((ushort4*)out)[i] = o;
}

__global__ void conv_gruw(const float* __restrict__ p0, const float* __restrict__ p1,
                          const float* __restrict__ p2, const float* __restrict__ p3,
                          __hip_bfloat16* __restrict__ out) {
  int idx = blockIdx.x * 256 + threadIdx.x;  // 786432 total
  int w = idx / 196608, r = idx - w * 196608;
  const float* s = (w == 0) ? p0 : (w == 1) ? p1 : (w == 2) ? p2 : p3;
  out[idx] = f2b(s[r]);
}

__global__ void conv_strided(const float* __restrict__ in, __hip_bfloat16* __restrict__ out,
                             int rows, int cols, int ld, int coff) {
  int idx = blockIdx.x * 256 + threadIdx.x;
  if (idx >= rows * cols) return;
  int r = idx / cols, c = idx - r * cols;
  out[idx] = f2b(in[(size_t)r * ld + coff + c]);
}

// ---------------- gemm256: C = A1*B1^T (+ A2*B2^T), used for GAT z (+esed) and OUT ----
#define EPI_ESED 0
#define EPI_OUT  1

template <int EPI, bool DUAL>
__global__ __launch_bounds__(256) void gemm256(
    const __hip_bfloat16* __restrict__ A1, const __hip_bfloat16* __restrict__ B1,
    const __hip_bfloat16* __restrict__ A2, const __hip_bfloat16* __restrict__ B2,
    void* __restrict__ Cv, int M, int N,
    const float* __restrict__ bi, const float* __restrict__ bh,
    float* __restrict__ ESp, float* __restrict__ EDp) {
  __shared__ __align__(16) short smem[16384];  // 2 bufs x (As[128][32] + Bs[128][32])
  const int tid = threadIdx.x;
  const int wid = tid >> 6, lane = tid & 63;

  // XCD-chunked bijective swizzle (m204)
  const int NW = gridDim.x * gridDim.y;
  const int wg = blockIdx.x + gridDim.x * blockIdx.y;
  const int q = NW >> 3, r8 = NW & 7;
  const int xcd = wg & 7, jj = wg >> 3;
  const int wid2 = (xcd < r8 ? xcd * (q + 1) : r8 * (q + 1) + (xcd - r8) * q) + jj;
  const int m0 = (wid2 / gridDim.x) * 128, n0 = (wid2 % gridDim.x) * 128;

  const int wr = wid >> 1, wc = wid & 1;
  const int sr = lane >> 2;
  const int kp = (((lane & 3) ^ ((lane >> 3) & 3)) * 8);   // staging: pre-swizzled k-chunk
  const int lrow = lane & 15;
  const int lk = (((lane >> 4) ^ ((lane >> 1) & 3)) * 8);  // read: same XOR
  const int NS = DUAL ? 16 : 8;
  f32x4 acc[4][4];
#pragma unroll
  for (int i = 0; i < 4; ++i)
#pragma unroll
    for (int j2 = 0; j2 < 4; ++j2) acc[i][j2] = (f32x4)0.f;

  auto stage = [&](int s, int buf) {
    const __hip_bfloat16* A = (DUAL && s >= 8) ? A2 : A1;
    const __hip_bfloat16* B = (DUAL && s >= 8) ? B2 : B1;
    const int k0 = (s & 7) * 32;
    short* As = smem + buf * 8192;
    short* Bs = As + 4096;
#pragma unroll
    for (int ss = 0; ss < 2; ++ss) {
      int seg = wid + ss * 4;
      gload16(A + (size_t)(m0 + seg * 16 + sr) * 256 + k0 + kp, &As[seg * 512]);
      gload16(B + (size_t)(n0 + seg * 16 + sr) * 256 + k0 + kp, &Bs[seg * 512]);
    }
  };

  auto compute = [&](int s) {
    const short* As = smem + (s & 1) * 8192;
    const short* Bs = As + 4096;
    short8 af[4], bfv[4];
#pragma unroll
    for (int i = 0; i < 4; ++i) af[i] = *(const short8*)&As[(wr * 64 + i * 16 + lrow) * 32 + lk];
#pragma unroll
    for (int j2 = 0; j2 < 4; ++j2) bfv[j2] = *(const short8*)&Bs[(wc * 64 + j2 * 16 + lrow) * 32 + lk];
#pragma unroll
    for (int i = 0; i < 4; ++i)
#pragma unroll
      for (int j2 = 0; j2 < 4; ++j2)
        acc[i][j2] = __builtin_amdgcn_mfma_f32_16x16x32_bf16(af[i], bfv[j2], acc[i][j2], 0, 0, 0);
  };

  stage(0, 0);
  stage(1, 1);
  for (int s = 0; s < NS - 1; ++s) {
    asm volatile("s_waitcnt vmcnt(4)" ::: "memory");
    __builtin_amdgcn_s_barrier();
    __builtin_amdgcn_sched_barrier(0);
    compute(s);
    asm volatile("s_waitcnt lgkmcnt(0)" ::: "memory");
    __builtin_amdgcn_sched_barrier(0);
    __builtin_amdgcn_s_barrier();
    if (s + 2 < NS) stage(s + 2, s & 1);
  }
  asm volatile("s_waitcnt vmcnt(0)" ::: "memory");
  __builtin_amdgcn_s_barrier();
  __builtin_amdgcn_sched_barrier(0);
  compute(NS - 1);

  const int rowb = m0 + wr * 64 + (lane >> 4) * 4;
  const int colb = n0 + wc * 64 + (lane & 15);

  if constexpr (EPI == EPI_ESED) {
    const int head = n0 >> 7;
#pragma unroll
    for (int i = 0; i < 4; ++i) {
#pragma unroll
      for (int rr = 0; rr < 4; ++rr) {
        const int row = rowb + i * 16 + rr;
        float ps = 0.f, pd = 0.f;
#pragma unroll
        for (int j2 = 0; j2 < 4; ++j2) {
          const int col = colb + j2 * 16;
          float v = acc[i][j2][rr];
          if (row < M) ((__hip_bfloat16*)Cv)[(size_t)row * N + col] = f2b(v);
          ps += v * bi[col];
          pd += v * bh[col];
        }
#pragma unroll
        for (int o = 8; o >= 1; o >>= 1) {
          ps += __shfl_xor(ps, o, 64);
          pd += __shfl_xor(pd, o, 64);
        }
        if ((lane & 15) == 0 && row < M) {
          atomicAdd(&ESp[row * 2 + head], ps);
          atomicAdd(&EDp[row * 2 + head], pd);
        }
      }
    }
    return;
  }

#pragma unroll
  for (int i = 0; i < 4; ++i) {
#pragma unroll
    for (int j2 = 0; j2 < 4; ++j2) {
      const int col = colb + j2 * 16;
#pragma unroll
      for (int rr = 0; rr < 4; ++rr) {
        const int row = rowb + i * 16 + rr;
        if (row >= M) continue;
        ((float*)Cv)[(size_t)row * 256 + col] = acc[i][j2][rr];
      }
    }
  }
}

// ---------------- fused GRU step: one kernel computes r,z,n and the gate math ----------
// STEP=1: out = (1-z)*tanh(gi_n + bi_n + r*bh_n), gi = h@Wi (h_prev = 0)
// STEP=2: gi = h@Wi (pass 0), gh = hp@Wh (pass 1); r,z accumulate across both passes;
//         out = hp + (1-z)*n + z*hp  (h_seq sum contribution)
// Block: 64 rows x 128 cols, 3 B-panels (r,z,n rows of W) per pass. Dual-direction
// launch: gridDim.x = 4, dir = blockIdx-col>>1.
template <int STEP>
__global__ __launch_bounds__(256) void gru_fused(
    const __hip_bfloat16* __restrict__ hF, const __hip_bfloat16* __restrict__ WiF,
    const __hip_bfloat16* __restrict__ hpF, const __hip_bfloat16* __restrict__ WhF,
    const float* __restrict__ biF, const float* __restrict__ bhF,
    __hip_bfloat16* __restrict__ outF,
    const __hip_bfloat16* __restrict__ hB, const __hip_bfloat16* __restrict__ WiB,
    const __hip_bfloat16* __restrict__ hpB, const __hip_bfloat16* __restrict__ WhB,
    const float* __restrict__ biB, const float* __restrict__ bhB,
    __hip_bfloat16* __restrict__ outB) {
  __shared__ __align__(16) short smem[28672];  // 2 bufs x (As[64][32] + Bs[3][128][32])
  const int tid = threadIdx.x;
  const int wid = tid >> 6, lane = tid & 63;

  // XCD swizzle
  const int NW = gridDim.x * gridDim.y;
  const int wg = blockIdx.x + gridDim.x * blockIdx.y;
  const int q = NW >> 3, r8 = NW & 7;
  const int xcd = wg & 7, jj = wg >> 3;
  const int wid2 = (xcd < r8 ? xcd * (q + 1) : r8 * (q + 1) + (xcd - r8) * q) + jj;
  const int bx2 = wid2 & 3;
  const int m0 = (wid2 >> 2) * 64;
  const int dir = bx2 >> 1;
  const int n0c = (bx2 & 1) * 128;

  const __hip_bfloat16* Ah = dir ? hB : hF;
  const __hip_bfloat16* Wi = dir ? WiB : WiF;
  const __hip_bfloat16* Ahp = dir ? hpB : hpF;
  const __hip_bfloat16* Wh = dir ? WhB : WhF;
  const float* bi = dir ? biB : biF;
  const float* bh = dir ? bhB : bhF;
  __hip_bfloat16* outp = dir ? outB : outF;

  const int wr = wid >> 1, wc = wid & 1;
  const int sr = lane >> 2;
  const int kp = (((lane & 3) ^ ((lane >> 3) & 3)) * 8);
  const int lrow = lane & 15;
  const int lk = (((lane >> 4) ^ ((lane >> 1) & 3)) * 8);
  const int NS = (STEP == 1) ? 8 : 16;

  f32x4 acc[(STEP == 1) ? 3 : 4][2][4];
#pragma unroll
  for (int a = 0; a < ((STEP == 1) ? 3 : 4); ++a)
#pragma unroll
    for (int i = 0; i < 2; ++i)
#pragma unroll
      for (int j = 0; j < 4; ++j) acc[a][i][j] = (f32x4)0.f;

  auto stage = [&](int s, int buf) {
    const __hip_bfloat16* A = (STEP == 2 && s >= 8) ? Ahp : Ah;
    const __hip_bfloat16* W = (STEP == 2 && s >= 8) ? Wh : Wi;
    const int k0 = (s & 7) * 32;
    short* As = smem + buf * 14336;
    short* Bs = As + 2048;
    // A: 64 rows = 4 segs of 16; this wave stages seg=wid (1 issue)
    gload16(A + (size_t)(m0 + wid * 16 + sr) * 256 + k0 + kp, &As[wid * 512]);
    // B: 3 panels x 8 segs = 24; this wave stages 6 (seg = wid + ss*4)
#pragma unroll
    for (int ss = 0; ss < 6; ++ss) {
      int seg = wid + ss * 4;
      int p = seg >> 3, sub = seg & 7;
      int grow = p * 256 + n0c + sub * 16 + sr;   // row in W (768 x 256)
      gload16(W + (size_t)grow * 256 + k0 + kp, &Bs[seg * 512]);
    }
  };

  auto computeP = [&](int s, auto PN) {   // PN: integral_constant pass index
    constexpr int pn = decltype(PN)::value;
    const short* As = smem + (s & 1) * 14336;
    const short* Bs = As + 2048;
    short8 af[2];
#pragma unroll
    for (int i = 0; i < 2; ++i)
      af[i] = *(const short8*)&As[(wr * 32 + i * 16 + lrow) * 32 + lk];
#pragma unroll
    for (int p = 0; p < 3; ++p) {
      short8 bf[4];
#pragma unroll
      for (int j = 0; j < 4; ++j)
        bf[j] = *(const short8*)&Bs[p * 4096 + (wc * 64 + j * 16 + lrow) * 32 + lk];
      constexpr int base = (STEP == 1) ? 0 : 0;
      const int ap = (p < 2) ? p : ((STEP == 1) ? 2 : (2 + pn));
      (void)base;
#pragma unroll
      for (int i = 0; i < 2; ++i)
#pragma unroll
        for (int j = 0; j < 4; ++j)
          acc[ap][i][j] = __builtin_amdgcn_mfma_f32_16x16x32_bf16(af[i], bf[j], acc[ap][i][j], 0, 0, 0);
    }
  };

  stage(0, 0);
  stage(1, 1);
  for (int s = 0; s < NS - 1; ++s) {
    asm volatile("s_waitcnt vmcnt(7)" ::: "memory");
    __builtin_amdgcn_s_barrier();
    __builtin_amdgcn_sched_barrier(0);
    if (STEP == 2 && s >= 8) computeP(s, std::integral_constant<int, 1>{});
    else computeP(s, std::integral_constant<int, 0>{});
    asm volatile("s_waitcnt lgkmcnt(0)" ::: "memory");
    __builtin_amdgcn_sched_barrier(0);
    __builtin_amdgcn_s_barrier();
    if (s + 2 < NS) stage(s + 2, s & 1);
  }
  asm volatile("s_waitcnt vmcnt(0)" ::: "memory");
  __builtin_amdgcn_s_barrier();
  __builtin_amdgcn_sched_barrier(0);
  if (STEP == 2) computeP(NS - 1, std::integral_constant<int, 1>{});
  else computeP(NS - 1, std::integral_constant<int, 0>{});

  const int rowb = m0 + wr * 32 + (lane >> 4) * 4;
  const int colb = n0c + wc * 64 + (lane & 15);
#pragma unroll
  for (int i = 0; i < 2; ++i) {
#pragma unroll
    for (int j = 0; j < 4; ++j) {
      const int col = colb + j * 16;
      const float bir = bi[col], bhr = bh[col];
      const float biz = bi[256 + col], bhz = bh[256 + col];
      const float bin = bi[512 + col], bhn = bh[512 + col];
#pragma unroll
      for (int rr = 0; rr < 4; ++rr) {
        const int row = rowb + i * 16 + rr;
        if (row >= NN) continue;
        float r_ = sigm(acc[0][i][j][rr] + bir + bhr);
        float z_ = sigm(acc[1][i][j][rr] + biz + bhz);
        if constexpr (STEP == 1) {
          float n_ = tanhf(acc[2][i][j][rr] + bin + r_ * bhn);
          outp[(size_t)row * 256 + col] = f2b((1.f - z_) * n_);
        } else {
          float n_ = tanhf(acc[2][i][j][rr] + bin + r_ * (acc[3][i][j][rr] + bhn));
          float hp = b2f(Ahp[(size_t)row * 256 + col]);
          outp[(size_t)row * 256 + col] = f2b(hp + (1.f - z_) * n_ + z_ * hp);
        }
      }
    }
  }
}

// ---------------- CSR build ----------------
__global__ void hist_kernel(const int* __restrict__ dst, int* __restrict__ deg, int ne) {
  for (int e = blockIdx.x * blockDim.x + threadIdx.x; e < ne; e += gridDim.x * blockDim.x)
    atomicAdd(&deg[dst[e]], 1);
}

__global__ void scan1(const int* __restrict__ deg, int* __restrict__ bsum, int n) {
  __shared__ int sd[256];
  int idx = blockIdx.x * 256 + threadIdx.x;
  sd[threadIdx.x] = (idx < n) ? deg[idx] : 0;
  __syncthreads();
  for (int off = 128; off > 0; off >>= 1) {
    if (threadIdx.x < off) sd[threadIdx.x] += sd[threadIdx.x + off];
    __syncthreads();
  }
  if (threadIdx.x == 0) bsum[blockIdx.x] = sd[0];
}

__global__ void scan2(const int* __restrict__ bsum, int* __restrict__ boff, int nb) {
  __shared__ int s[256];
  int t = threadIdx.x;
  int v0 = (t < nb) ? bsum[t] : 0;
  s[t] = v0;
  __syncthreads();
  for (int off = 1; off < 256; off <<= 1) {
    int x = (t >= off) ? s[t - off] : 0;
    __syncthreads();
    s[t] += x;
    __syncthreads();
  }
  if (t < nb) boff[t] = s[t] - v0;
}

__global__ void scan3(const int* __restrict__ deg, const int* __restrict__ boff,
                      int* __restrict__ row_ptr, int* __restrict__ cursor, int n, int ne) {
  __shared__ int s[256];
  int t = threadIdx.x;
  int idx = blockIdx.x * 256 + t;
  int v = (idx < n) ? deg[idx] : 0;
  s[t] = v;
  __syncthreads();
  for (int off = 1; off < 256; off <<= 1) {
    int x = (t >= off) ? s[t - off] : 0;
    __syncthreads();
    s[t] += x;
    __syncthreads();
  }
  if (idx < n) {
    int val = boff[blockIdx.x] + s[t] - v;
    row_ptr[idx] = val;
    cursor[idx] = val;
  }
  if (idx == n) row_ptr[n] = ne;
}

__global__ void scatter_kernel(const int* __restrict__ src, const int* __restrict__ dst,
                               int* __restrict__ cursor, int* __restrict__ srcs, int ne) {
  for (int e = blockIdx.x * blockDim.x + threadIdx.x; e < ne; e += gridDim.x * blockDim.x) {
    int p = atomicAdd(&cursor[dst[e]], 1);
    srcs[p] = src[e];
  }
}

// ---------------- GAT aggregation: one wave per node ----------------
__device__ __forceinline__ void onl_upd(float& m, float& s, float v) {
  if (v <= m) {
    s += __expf(v - m);
  } else {
    s = s * __expf(m - v) + 1.f;
    m = v;
  }
}

__global__ __launch_bounds__(256) void gat_agg_wave(const int* __restrict__ row_ptr,
                                                    const int* __restrict__ srcs,
                                                    const float* __restrict__ es,
                                                    const float* __restrict__ ed,
                                                    const __hip_bfloat16* __restrict__ z,
                                                    __hip_bfloat16* __restrict__ hout) {
  int node = blockIdx.x * 4 + (threadIdx.x >> 6);
  int lane = threadIdx.x & 63;
  if (node >= NN) return;
  ushort4* outp = (ushort4*)&hout[(size_t)node * 256 + lane * 4];
  int start = row_ptr[node], end = row_ptr[node + 1];
  int deg = end - start;
  if (deg == 0) {
    *outp = make_ushort4(0, 0, 0, 0);
    return;
  }
  float ed0 = ed[node * 2], ed1 = ed[node * 2 + 1];
  int h = lane >> 5;
  float a0 = 0.f, a1 = 0.f, a2 = 0.f, a3 = 0.f;

  if (deg <= 64) {
    int sn = 0;
    float l0 = -1e30f, l1 = -1e30f;
    if (lane < deg) {
      sn = srcs[start + lane];
      float2 ee = *(const float2*)&es[sn * 2];
      l0 = leaky(ee.x + ed0);
      l1 = leaky(ee.y + ed1);
    }
    float m0 = l0, m1 = l1;
#pragma unroll
    for (int off = 32; off > 0; off >>= 1) {
      m0 = fmaxf(m0, __shfl_xor(m0, off, 64));
      m1 = fmaxf(m1, __shfl_xor(m1, off, 64));
    }
    float p0 = (lane < deg) ? __expf(l0 - m0) : 0.f;
    float p1 = (lane < deg) ? __expf(l1 - m1) : 0.f;
    float s0 = p0, s1 = p1;
#pragma unroll
    for (int off = 32; off > 0; off >>= 1) {
      s0 += __shfl_xor(s0, off, 64);
      s1 += __shfl_xor(s1, off, 64);
    }
    float w0 = p0 / s0, w1 = p1 / s1;
    const size_t zlo = lane * 4;
    int e = 0;
    for (; e + 4 <= deg; e += 4) {
      int sa = __shfl(sn, e, 64), sb = __shfl(sn, e + 1, 64);
      int sc = __shfl(sn, e + 2, 64), sd = __shfl(sn, e + 3, 64);
      float wa0 = __shfl(w0, e, 64),     wa1 = __shfl(w1, e, 64);
      float wb0 = __shfl(w0, e + 1, 64), wb1 = __shfl(w1, e + 1, 64);
      float wc0 = __shfl(w0, e + 2, 64), wc1 = __shfl(w1, e + 2, 64);
      float wd0 = __shfl(w0, e + 3, 64), wd1 = __shfl(w1, e + 3, 64);
      float wa = h ? wa1 : wa0;
      float wb = h ? wb1 : wb0;
      float wc = h ? wc1 : wc0;
      float wd = h ? wd1 : wd0;
      ushort4 za = *(const ushort4*)&z[(size_t)sa * 256 + zlo];
      ushort4 zb = *(const ushort4*)&z[(size_t)sb * 256 + zlo];
      ushort4 zc = *(const ushort4*)&z[(size_t)sc * 256 + zlo];
      ushort4 zd = *(const ushort4*)&z[(size_t)sd * 256 + zlo];
      a0 = fmaf(wa, bu2f(za.x), a0); a1 = fmaf(wa, bu2f(za.y), a1);
      a2 = fmaf(wa, bu2f(za.z), a2); a3 = fmaf(wa, bu2f(za.w), a3);
      a0 = fmaf(wb, bu2f(zb.x), a0); a1 = fmaf(wb, bu2f(zb.y), a1);
      a2 = fmaf(wb, bu2f(zb.z), a2); a3 = fmaf(wb, bu2f(zb.w), a3);
      a0 = fmaf(wc, bu2f(zc.x), a0); a1 = fmaf(wc, bu2f(zc.y), a1);
      a2 = fmaf(wc, bu2f(zc.z), a2); a3 = fmaf(wc, bu2f(zc.w), a3);
      a0 = fmaf(wd, bu2f(zd.x), a0); a1 = fmaf(wd, bu2f(zd.y), a1);
      a2 = fmaf(wd, bu2f(zd.z), a2); a3 = fmaf(wd, bu2f(zd.w), a3);
    }
    for (; e < deg; ++e) {
      int sa = __shfl(sn, e, 64);
      float wa0 = __shfl(w0, e, 64), wa1 = __shfl(w1, e, 64);
      float wa = h ? wa1 : wa0;
      ushort4 za = *(const ushort4*)&z[(size_t)sa * 256 + zlo];
      a0 = fmaf(wa, bu2f(za.x), a0); a1 = fmaf(wa, bu2f(za.y), a1);
      a2 = fmaf(wa, bu2f(za.z), a2); a3 = fmaf(wa, bu2f(za.w), a3);
    }
  } else {
    float m0 = -1e30f, s0 = 0.f, m1 = -1e30f, s1 = 0.f;
    for (int i = start + lane; i < end; i += 64) {
      int sn = srcs[i];
      float e0 = es[sn * 2], e1 = es[sn * 2 + 1];
      onl_upd(m0, s0, leaky(e0 + ed0));
      onl_upd(m1, s1, leaky(e1 + ed1));
    }
#pragma unroll
    for (int off = 32; off > 0; off >>= 1) {
      float om0 = __shfl_xor(m0, off, 64), os0 = __shfl_xor(s0, off, 64);
      float om1 = __shfl_xor(m1, off, 64), os1 = __shfl_xor(s1, off, 64);
      float mm = fmaxf(m0, om0);
      s0 = s0 * __expf(m0 - mm) + os0 * __expf(om0 - mm);
      m0 = mm;
      mm = fmaxf(m1, om1);
      s1 = s1 * __expf(m1 - mm) + os1 * __expf(om1 - mm);
      m1 = mm;
    }
    float rm = h ? m1 : m0;
    float rsi = 1.f / (h ? s1 : s0);
    float edh = h ? ed1 : ed0;
    for (int e = start; e < end; ++e) {
      int sa = srcs[e];
      float2 ee = *(const float2*)&es[sa * 2];
      float w = __expf(leaky((h ? ee.y : ee.x) + edh) - rm) * rsi;
      ushort4 zv = *(const ushort4*)&z[(size_t)sa * 256 + lane * 4];
      a0 = fmaf(w, bu2f(zv.x), a0); a1 = fmaf(w, bu2f(zv.y), a1);
      a2 = fmaf(w, bu2f(zv.z), a2); a3 = fmaf(w, bu2f(zv.w), a3);
    }
  }
  ushort4 o;
  o.x = f2bu(fmaxf(a0, 0.f));
  o.y = f2bu(fmaxf(a1, 0.f));
  o.z = f2bu(fmaxf(a2, 0.f));
  o.w = f2bu(fmaxf(a3, 0.f));
  *outp = o;
}

// ---------------- host ----------------
extern "C" void kernel_launch(void* const* d_in, const int* in_sizes, int n_in,
                              void* d_out, int out_size, void* d_ws, size_t ws_size,
                              hipStream_t stream) {
  const float* in_feat = (const float*)d_in[0];
  const int* srcp = (const int*)d_in[1];
  const int* dstp = (const int*)d_in[2];
  const float* W1 = (const float*)d_in[3];
  const float* as1 = (const float*)d_in[4];
  const float* ad1 = (const float*)d_in[5];
  const float* W2 = (const float*)d_in[6];
  const float* as2 = (const float*)d_in[7];
  const float* ad2 = (const float*)d_in[8];
  const float* wi_f = (const float*)d_in[9];
  const float* wh_f = (const float*)d_in[10];
  const float* bi_f = (const float*)d_in[11];
  const float* bh_f = (const float*)d_in[12];
  const float* wi_b = (const float*)d_in[13];
  const float* wh_b = (const float*)d_in[14];
  const float* bi_b = (const float*)d_in[15];
  const float* bh_b = (const float*)d_in[16];
  // d_in[17] = s_w: dead (softmax over a singleton axis == 1.0)
  const float* lin_w = (const float*)d_in[18];
  (void)in_sizes; (void)n_in; (void)out_size;

  const size_t UNIT = (size_t)MP * 256 * 2;
  char* ws = (char*)d_ws;
  size_t off = 0;
  auto take = [&](size_t bytes) -> void* {
    void* p = ws + off;
    off += (bytes + 255) & ~(size_t)255;
    return p;
  };
  __hip_bfloat16* U0 = (__hip_bfloat16*)take(UNIT);      // x, then fsum
  __hip_bfloat16* U1 = (__hip_bfloat16*)take(UNIT * 2);  // z (GAT), then bsum
  __hip_bfloat16* h1 = (__hip_bfloat16*)take(UNIT);
  __hip_bfloat16* h2 = (__hip_bfloat16*)take(UNIT);
  __hip_bfloat16* hpF = (__hip_bfloat16*)take(UNIT);     // f0
  __hip_bfloat16* hpB = (__hip_bfloat16*)take(UNIT);     // b1
  __hip_bfloat16* wW1 = (__hip_bfloat16*)take(65536 * 2);
  __hip_bfloat16* wW2 = (__hip_bfloat16*)take(65536 * 2);
  __hip_bfloat16* wif = (__hip_bfloat16*)take(196608 * 2);  // conv_gruw order: wif,whf,wib,whb
  __hip_bfloat16* whf = (__hip_bfloat16*)take(196608 * 2);
  __hip_bfloat16* wib = (__hip_bfloat16*)take(196608 * 2);
  __hip_bfloat16* whb = (__hip_bfloat16*)take(196608 * 2);
  __hip_bfloat16* wlinA = (__hip_bfloat16*)take(65536 * 2);
  __hip_bfloat16* wlinB = (__hip_bfloat16*)take(65536 * 2);
  int* deg = (int*)take((size_t)NN * 4);
  float* es1 = (float*)take((size_t)NN * 2 * 4);
  float* ed1 = (float*)take((size_t)NN * 2 * 4);
  float* es2 = (float*)take((size_t)NN * 2 * 4);
  float* ed2 = (float*)take((size_t)NN * 2 * 4);
  int* cursor = (int*)take((size_t)NN * 4);
  int* row_ptr = (int*)take((size_t)(NN + 1) * 4);
  int* bsum = (int*)take(256 * 4);
  int* boff = (int*)take(256 * 4);
  int* srcs = (int*)take((size_t)NE * 4);

  if (off > ws_size) {
    diag_kernel<<<1, 1, 0, stream>>>((float*)d_out, (float)ws_size);
    return;
  }

  // conversions
  conv4_kernel<<<12500, 256, 0, stream>>>(in_feat, U0, NN * 64);
  conv_kernel<<<256, 256, 0, stream>>>(W1, wW1, 65536);
  conv_kernel<<<256, 256, 0, stream>>>(W2, wW2, 65536);
  conv_gruw<<<3072, 256, 0, stream>>>(wi_f, wh_f, wi_b, wh_b, wif);
  conv_strided<<<256, 256, 0, stream>>>(lin_w, wlinA, 256, 256, 512, 0);
  conv_strided<<<256, 256, 0, stream>>>(lin_w, wlinB, 256, 256, 512, 256);

  // zero deg + es/ed
  {
    int zw = (int)(((char*)ed2 - (char*)deg) / 4) + NN * 2;
    zero_i32<<<(zw + 255) / 256, 256, 0, stream>>>(deg, zw);
  }
  hist_kernel<<<1024, 256, 0, stream>>>(dstp, deg, NE);
  scan1<<<NBLK, 256, 0, stream>>>(deg, bsum, NN);
  scan2<<<1, 256, 0, stream>>>(bsum, boff, NBLK);
  scan3<<<NBLK, 256, 0, stream>>>(deg, boff, row_ptr, cursor, NN, NE);
  scatter_kernel<<<1024, 256, 0, stream>>>(srcp, dstp, cursor, srcs, NE);

  dim3 g2(2, MP / 128);

  // GAT layer 1
  gemm256<EPI_ESED, false><<<g2, 256, 0, stream>>>(U0, wW1, nullptr, nullptr, U1, NN, 256,
                                                   as1, ad1, es1, ed1);
  gat_agg_wave<<<12500, 256, 0, stream>>>(row_ptr, srcs, es1, ed1, U1, h1);
  // GAT layer 2
  gemm256<EPI_ESED, false><<<g2, 256, 0, stream>>>(h1, wW2, nullptr, nullptr, U1, NN, 256,
                                                   as2, ad2, es2, ed2);
  gat_agg_wave<<<12500, 256, 0, stream>>>(row_ptr, srcs, es2, ed2, U1, h2);

  // GRU step 1 (both directions): f0 = step(0,h1) -> hpF ; b1 = step(0,h2) -> hpB
  gru_fused<1><<<dim3(4, MP / 64), 256, 0, stream>>>(
      h1, wif, nullptr, nullptr, bi_f, bh_f, hpF,
      h2, wib, nullptr, nullptr, bi_b, bh_b, hpB);
  // GRU step 2 (both directions): fsum = f0 + step(f0,h2) -> U0 ; bsum = b1 + step(b1,h1) -> U1
  gru_fused<2><<<dim3(4, MP / 64), 256, 0, stream>>>(
      h2, wif, hpF, whf, bi_f, bh_f, U0,
      h1, wib, hpB, whb, bi_b, bh_b, U1);

  // out = fsum@linA^T + bsum@linB^T
  gemm256<EPI_OUT, true><<<g2, 256, 0, stream>>>(U0, wlinA, U1, wlinB, d_out, NN, 256,
                                                 nullptr, nullptr, nullptr, nullptr);
}